// Round 11
// baseline (266.092 us; speedup 1.0000x reference)
//
#include <hip/hip_runtime.h>
#include <hip/hip_fp16.h>
#include <math.h>

#define N_DRUG 20000
#define N_PROT 30000
#define NN (N_DRUG + N_PROT)
#define F_DRUG 128
#define F_PROT 256
#define H 64
#define NE 1600000
#define NL 200000

#define NB_PROJD ((N_DRUG + 127) / 128)          // 157 (128 rows/block)
#define NB_PROJP ((N_PROT + 127) / 128)          // 235
#define NB_ROW4  (NN / 4)                        // 12500 (4 rows/block, warp per row; NN%4==0)
#define NBK1 256                                  // partition chunks
#define CH   ((NE + NBK1 - 1) / NBK1)            // 6250 edges/chunk
#define NB_BKT ((NN + 255) / 256)                // 196 buckets

typedef _Float16 h8 __attribute__((ext_vector_type(8)));
typedef _Float16 h4 __attribute__((ext_vector_type(4)));
typedef float f32x4 __attribute__((ext_vector_type(4)));

#define MFMA16(a, b, c) __builtin_amdgcn_mfma_f32_16x16x32_f16((a), (b), (c), 0, 0, 0)

// ---------------- weight prep ----------------
// wdt/wpt: transposed [c][k] fp16 for the MFMA projections.
// cwt: conv weights straight-cast to fp16, ROW-major [l][f][c] (epilogue W-mult).
__global__ __launch_bounds__(256) void k_wprep(
    const float* __restrict__ Wd, const float* __restrict__ Wp,
    const float* __restrict__ cw,
    _Float16* __restrict__ wdt, _Float16* __restrict__ wpt,
    _Float16* __restrict__ cwt) {
    int i = blockIdx.x * 256 + threadIdx.x;
    if (i < 64 * F_DRUG) {
        int c = i / F_DRUG, k = i % F_DRUG;
        wdt[i] = (_Float16)Wd[k * H + c];
    }
    if (i < 64 * F_PROT) {
        int c = i / F_PROT, k = i % F_PROT;
        wpt[i] = (_Float16)Wp[k * H + c];
    }
    if (i < 3 * 64 * 64) {
        cwt[i] = (_Float16)cw[i];
    }
}

// ---------------- zero-LDS MFMA projection: out = relu(X@W + b) as fp16 [row][64] ----------------
template <int F>
__device__ __forceinline__ void proj_direct(
    const float* __restrict__ X, const _Float16* __restrict__ Wt,
    const float* __restrict__ bias, _Float16* __restrict__ out,
    int rows, int row_off, int bid) {
    int l = threadIdx.x & 63, wvi = threadIdx.x >> 6;
    int lr = l & 15, lq = l >> 4;
    int r0 = bid * 128 + wvi * 32;
    f32x4 acc[2][4];
    #pragma unroll
    for (int rt = 0; rt < 2; ++rt)
        #pragma unroll
        for (int n = 0; n < 4; ++n) acc[rt][n] = (f32x4){0.f, 0.f, 0.f, 0.f};

    for (int k0 = 0; k0 < F; k0 += 64) {
        h8 af[4][2];
        #pragma unroll
        for (int n = 0; n < 4; ++n)
            #pragma unroll
            for (int kk = 0; kk < 2; ++kk)
                af[n][kk] = *(const h8*)&Wt[(size_t)(n * 16 + lr) * F + k0 + kk * 32 + lq * 8];
        #pragma unroll
        for (int rt = 0; rt < 2; ++rt) {
            int r = r0 + rt * 16 + lr;
            int rc = (r < rows) ? r : (rows - 1);
            h8 bf[2];
            #pragma unroll
            for (int kk = 0; kk < 2; ++kk) {
                const float* xp = X + (size_t)rc * F + k0 + kk * 32 + lq * 8;
                float4 a = *(const float4*)xp;
                float4 b = *(const float4*)(xp + 4);
                h8 t;
                t[0] = (_Float16)a.x; t[1] = (_Float16)a.y;
                t[2] = (_Float16)a.z; t[3] = (_Float16)a.w;
                t[4] = (_Float16)b.x; t[5] = (_Float16)b.y;
                t[6] = (_Float16)b.z; t[7] = (_Float16)b.w;
                bf[kk] = t;
            }
            #pragma unroll
            for (int n = 0; n < 4; ++n) {
                acc[rt][n] = MFMA16(af[n][0], bf[0], acc[rt][n]);
                acc[rt][n] = MFMA16(af[n][1], bf[1], acc[rt][n]);
            }
        }
    }
    #pragma unroll
    for (int rt = 0; rt < 2; ++rt) {
        int r = r0 + rt * 16 + lr;
        if (r < rows) {
            #pragma unroll
            for (int n = 0; n < 4; ++n) {
                int c = n * 16 + lq * 4;
                float4 bv = *(const float4*)&bias[c];
                h4 hv;
                hv[0] = (_Float16)fmaxf(acc[rt][n][0] + bv.x, 0.f);
                hv[1] = (_Float16)fmaxf(acc[rt][n][1] + bv.y, 0.f);
                hv[2] = (_Float16)fmaxf(acc[rt][n][2] + bv.z, 0.f);
                hv[3] = (_Float16)fmaxf(acc[rt][n][3] + bv.w, 0.f);
                *(h4*)(out + (size_t)(row_off + r) * H + c) = hv;
            }
        }
    }
}

// ---------------- fused front: proj_drug || proj_prot || coarse bucket hist ----------------
__global__ __launch_bounds__(256) void k_front(
    const float* __restrict__ xd, const _Float16* __restrict__ wdt, const float* __restrict__ bd,
    const float* __restrict__ xp, const _Float16* __restrict__ wpt, const float* __restrict__ bp,
    const int* __restrict__ ei, unsigned* __restrict__ bhist, _Float16* __restrict__ xa) {
    __shared__ unsigned lh[256];
    int bid = blockIdx.x;
    if (bid < NB_PROJD) {
        proj_direct<F_DRUG>(xd, wdt, bd, xa, N_DRUG, 0, bid);
    } else if (bid < NB_PROJD + NB_PROJP) {
        proj_direct<F_PROT>(xp, wpt, bp, xa, N_PROT, N_DRUG, bid - NB_PROJD);
    } else {
        int blk = bid - NB_PROJD - NB_PROJP;
        int t = threadIdx.x;
        lh[t] = 0;
        __syncthreads();
        int eb = blk * CH, ee = min(NE, eb + CH);
        for (int e = eb + t; e < ee; e += 256)
            atomicAdd(&lh[((unsigned)ei[NE + e]) >> 8], 1u);
        __syncthreads();
        bhist[(size_t)t * NBK1 + blk] = lh[t];
    }
}

// ---------------- scan step A: per-bucket row sums ----------------
__global__ __launch_bounds__(256) void kA(const unsigned* __restrict__ bhist,
                                          unsigned* __restrict__ rsum) {
    __shared__ unsigned s[256];
    int j = blockIdx.x, t = threadIdx.x;
    s[t] = bhist[(size_t)j * NBK1 + t];
    __syncthreads();
    for (int off = 128; off; off >>= 1) {
        if (t < off) s[t] += s[t + off];
        __syncthreads();
    }
    if (t == 0) rsum[j] = s[0];
}

// ---------------- scan step C (merged B+C): bucket bases + per-bucket row scan ----------------
__global__ __launch_bounds__(256) void kC2(unsigned* __restrict__ bhist,
                                           const unsigned* __restrict__ rsum,
                                           unsigned* __restrict__ rbase) {
    __shared__ unsigned sb[256], s[256];
    int j = blockIdx.x, t = threadIdx.x;
    unsigned rc = rsum[t];
    sb[t] = rc;
    __syncthreads();
    for (int off = 1; off < 256; off <<= 1) {
        unsigned v = sb[t]; unsigned u = (t >= off) ? sb[t - off] : 0;
        __syncthreads(); sb[t] = v + u; __syncthreads();
    }
    if (j == 0) {
        rbase[t] = sb[t] - rc;
        if (t == 255) rbase[256] = sb[255];     // == NE
    }
    unsigned rb = (j > 0) ? sb[j - 1] : 0;       // this bucket's base
    unsigned c = bhist[(size_t)j * NBK1 + t];
    s[t] = c;
    __syncthreads();
    for (int off = 1; off < 256; off <<= 1) {
        unsigned v = s[t]; unsigned u = (t >= off) ? s[t - off] : 0;
        __syncthreads(); s[t] = v + u; __syncthreads();
    }
    bhist[(size_t)j * NBK1 + t] = rb + s[t] - c;
}

// ---------------- bucket partition-scatter, XCD-contiguous chunk remap ----------------
__global__ __launch_bounds__(256) void k_part(
    const int* __restrict__ ei, const unsigned* __restrict__ base,
    unsigned* __restrict__ tmp) {
    __shared__ unsigned lcur[256];
    int bid = blockIdx.x;
    int c = ((bid & 7) << 5) | (bid >> 3);   // XCD-contiguous chunk id
    int t = threadIdx.x;
    lcur[t] = base[(size_t)t * NBK1 + c];
    __syncthreads();
    int eb = c * CH, ee = min(NE, eb + CH);
    for (int e = eb + t; e < ee; e += 256) {
        unsigned s = (unsigned)ei[e];
        unsigned d = (unsigned)ei[NE + e];
        unsigned pos = atomicAdd(&lcur[d >> 8], 1u);
        tmp[pos] = ((d & 255u) << 16) | s;
    }
}

// ---------------- per-bucket CSR finalize: rp, dis, csr(u16) ----------------
__global__ __launch_bounds__(256) void k_csr(
    const unsigned* __restrict__ tmp, const unsigned* __restrict__ rbase,
    int* __restrict__ rp, float* __restrict__ dis,
    unsigned short* __restrict__ csr) {
    __shared__ unsigned lbin[256], lofs[256], lcur[256];
    int b = blockIdx.x, t = threadIdx.x;
    unsigned nb0 = rbase[b], nb1 = rbase[b + 1];
    lbin[t] = 0;
    __syncthreads();
    for (unsigned i = nb0 + t; i < nb1; i += 256)
        atomicAdd(&lbin[tmp[i] >> 16], 1u);
    __syncthreads();
    unsigned c = lbin[t];
    lofs[t] = c;
    __syncthreads();
    for (int off = 1; off < 256; off <<= 1) {
        unsigned v = lofs[t]; unsigned u = (t >= off) ? lofs[t - off] : 0;
        __syncthreads(); lofs[t] = v + u; __syncthreads();
    }
    unsigned r = nb0 + lofs[t] - c;
    int node = b * 256 + t;
    if (node < NN) {
        rp[node] = (int)r;
        dis[node] = rsqrtf((float)c + 1.0f);
    }
    lcur[t] = r;
    __syncthreads();
    for (unsigned i = nb0 + t; i < nb1; i += 256) {
        unsigned rec = tmp[i];
        unsigned pos = atomicAdd(&lcur[rec >> 16], 1u);
        csr[pos] = (unsigned short)(rec & 0xffffu);
    }
    if (b == 0 && t == 0) rp[NN] = NE;
}

// ---------------- SpMM with fused conv: x_out = relu((Â x_in) @ W + b) ----------------
// Quarter q (16 lanes) walks edges idx = beg+q, +4, ... Each lane holds features 4g..4g+3.
// Broadcast pack load (16 lanes same addr = 1 request), then 128B row gather.
// Epilogue: quarter-reduce -> self term -> LDS row broadcast -> W-mult (f-split by quarter)
// -> quarter-reduce -> bias+relu -> store (or LAST: lin head dot -> y).
template <bool FIRST, bool LAST>
__global__ __launch_bounds__(256) void k_spmm3(
    const int* __restrict__ rp, const unsigned short* __restrict__ csr,
    unsigned* __restrict__ pack, const float* __restrict__ dis,
    const _Float16* __restrict__ xin, const _Float16* __restrict__ Wl,
    const float* __restrict__ bias, _Float16* __restrict__ xout,
    const float* __restrict__ lw, const float* __restrict__ lb,
    float* __restrict__ y) {
    __shared__ float rowbuf[4][64];
    int lane = threadIdx.x & 63, wrp = threadIdx.x >> 6;
    int d = blockIdx.x * 4 + wrp;            // NN % 4 == 0: always valid
    int q = lane >> 4, g = lane & 15;
    int beg = rp[d], end = rp[d + 1];
    float dd = dis[d];
    float ax = 0.f, ay = 0.f, az = 0.f, aw = 0.f;

    #pragma unroll 4
    for (int idx = beg + q; idx < end; idx += 4) {
        int s; float w;
        if (FIRST) {
            s = csr[idx];
            w = dis[s] * dd;
            if (g == 0)
                pack[idx] = (unsigned)s |
                            ((unsigned)__half_as_ushort(__float2half(w)) << 16);
        } else {
            unsigned r = pack[idx];
            s = (int)(r & 0xffffu);
            w = __half2float(__ushort_as_half((unsigned short)(r >> 16)));
        }
        h4 xv = *(const h4*)&xin[((unsigned)s << 6) + (g << 2)];
        ax += w * (float)xv[0];
        ay += w * (float)xv[1];
        az += w * (float)xv[2];
        aw += w * (float)xv[3];
    }
    // reduce across quarters -> full aggregate, replicated
    ax += __shfl_xor(ax, 16); ay += __shfl_xor(ay, 16);
    az += __shfl_xor(az, 16); aw += __shfl_xor(aw, 16);
    ax += __shfl_xor(ax, 32); ay += __shfl_xor(ay, 32);
    az += __shfl_xor(az, 32); aw += __shfl_xor(aw, 32);
    // self term (added once per lane, post-reduce)
    h4 xs = *(const h4*)&xin[((unsigned)d << 6) + (g << 2)];
    float sn = dd * dd;
    ax += sn * (float)xs[0]; ay += sn * (float)xs[1];
    az += sn * (float)xs[2]; aw += sn * (float)xs[3];

    // stage aggregated row in LDS (q==0 lanes), then W-mult with f-range split by quarter
    if (q == 0) *(float4*)&rowbuf[wrp][g << 2] = make_float4(ax, ay, az, aw);
    __syncthreads();
    float o0 = 0.f, o1 = 0.f, o2 = 0.f, o3 = 0.f;
    #pragma unroll
    for (int t = 0; t < 4; ++t) {
        int f0 = (q << 4) + (t << 2);
        float4 rv = *(const float4*)&rowbuf[wrp][f0];
        const float* rvp = (const float*)&rv;
        #pragma unroll
        for (int i = 0; i < 4; ++i) {
            h4 wv = *(const h4*)&Wl[(size_t)(f0 + i) * 64 + (g << 2)];
            float r = rvp[i];
            o0 += r * (float)wv[0];
            o1 += r * (float)wv[1];
            o2 += r * (float)wv[2];
            o3 += r * (float)wv[3];
        }
    }
    o0 += __shfl_xor(o0, 16); o1 += __shfl_xor(o1, 16);
    o2 += __shfl_xor(o2, 16); o3 += __shfl_xor(o3, 16);
    o0 += __shfl_xor(o0, 32); o1 += __shfl_xor(o1, 32);
    o2 += __shfl_xor(o2, 32); o3 += __shfl_xor(o3, 32);

    float4 bv = *(const float4*)&bias[g << 2];
    float vx = fmaxf(o0 + bv.x, 0.f);
    float vy = fmaxf(o1 + bv.y, 0.f);
    float vz = fmaxf(o2 + bv.z, 0.f);
    float vw = fmaxf(o3 + bv.w, 0.f);
    if (LAST) {
        float4 lv = *(const float4*)&lw[g << 2];
        float tt = vx * lv.x + vy * lv.y + vz * lv.z + vw * lv.w;
        tt += __shfl_xor(tt, 1); tt += __shfl_xor(tt, 2);
        tt += __shfl_xor(tt, 4); tt += __shfl_xor(tt, 8);
        if (lane == 0) y[d] = tt + lb[0];
    } else if (q == 0) {
        h4 hv;
        hv[0] = (_Float16)vx; hv[1] = (_Float16)vy;
        hv[2] = (_Float16)vz; hv[3] = (_Float16)vw;
        *(h4*)(xout + ((size_t)d << 6) + (g << 2)) = hv;
    }
}

// ---------------- edge scoring: sigmoid(y[src]*y[dst]) ----------------
__global__ void k_out(const float* __restrict__ y, const int* __restrict__ ls,
                      const int* __restrict__ ld, float* __restrict__ out) {
    int e = blockIdx.x * blockDim.x + threadIdx.x;
    if (e < NL) {
        float z = y[ls[e]] * y[ld[e]];
        out[e] = 1.f / (1.f + __expf(-z));
    }
}

static inline size_t up256(size_t x) { return (x + 255) & ~(size_t)255; }

extern "C" void kernel_launch(void* const* d_in, const int* in_sizes, int n_in,
                              void* d_out, int out_size, void* d_ws, size_t ws_size,
                              hipStream_t stream) {
    const float* x_drug = (const float*)d_in[0];
    const float* x_prot = (const float*)d_in[1];
    const float* W_drug = (const float*)d_in[2];
    const float* b_drug = (const float*)d_in[3];
    const float* W_prot = (const float*)d_in[4];
    const float* b_prot = (const float*)d_in[5];
    const float* conv_W = (const float*)d_in[6];
    const float* conv_b = (const float*)d_in[7];
    const float* lin_W  = (const float*)d_in[8];
    const float* lin_b  = (const float*)d_in[9];
    const int*   ei     = (const int*)d_in[10];
    const int*   lsrc   = (const int*)d_in[11];
    const int*   ldst   = (const int*)d_in[12];
    float* out = (float*)d_out;

    char* w = (char*)d_ws;
    size_t off = 0;
    unsigned* bhist = (unsigned*)(w + off); off = up256(off + (size_t)256 * NBK1 * 4);
    unsigned* rsum  = (unsigned*)(w + off); off = up256(off + 256 * 4);
    unsigned* rbase = (unsigned*)(w + off); off = up256(off + 257 * 4);
    unsigned* tmp   = (unsigned*)(w + off); off = up256(off + (size_t)NE * 4);
    unsigned short* csr = (unsigned short*)(w + off); off = up256(off + (size_t)NE * 2);
    unsigned* pack  = (unsigned*)(w + off); off = up256(off + (size_t)NE * 4);
    int*    rp   = (int*)(w + off);    off = up256(off + (size_t)(NN + 1) * 4);
    float*  dis  = (float*)(w + off);  off = up256(off + (size_t)NN * 4);
    _Float16* xa = (_Float16*)(w + off); off = up256(off + (size_t)NN * H * 2);
    _Float16* xb = (_Float16*)(w + off); off = up256(off + (size_t)NN * H * 2);
    float*  y    = (float*)(w + off);  off = up256(off + (size_t)NN * 4);
    _Float16* wdt = (_Float16*)(w + off); off = up256(off + (size_t)64 * F_DRUG * 2);
    _Float16* wpt = (_Float16*)(w + off); off = up256(off + (size_t)64 * F_PROT * 2);
    _Float16* cwt = (_Float16*)(w + off); off = up256(off + (size_t)3 * 64 * 64 * 2);

    k_wprep<<<64, 256, 0, stream>>>(W_drug, W_prot, conv_W, wdt, wpt, cwt);

    // proj_drug || proj_prot || coarse hist
    k_front<<<NB_PROJD + NB_PROJP + NBK1, 256, 0, stream>>>(
        x_drug, wdt, b_drug, x_prot, wpt, b_prot, ei, bhist, xa);

    kA<<<256, 256, 0, stream>>>(bhist, rsum);
    kC2<<<256, 256, 0, stream>>>(bhist, rsum, rbase);

    // bucket partition-scatter (XCD-contiguous chunks)
    k_part<<<NBK1, 256, 0, stream>>>(ei, bhist, tmp);

    // per-bucket CSR finalize (rp, dis, u16 src)
    k_csr<<<NB_BKT, 256, 0, stream>>>(tmp, rbase, rp, dis, csr);

    // layer 0: xa -> xb (builds pack)
    k_spmm3<true, false><<<NB_ROW4, 256, 0, stream>>>(
        rp, csr, pack, dis, xa, cwt, conv_b, xb, nullptr, nullptr, nullptr);
    // layer 1: xb -> xa
    k_spmm3<false, false><<<NB_ROW4, 256, 0, stream>>>(
        rp, csr, pack, dis, xb, cwt + 4096, conv_b + 64, xa, nullptr, nullptr, nullptr);
    // layer 2: xa -> y (fused lin head)
    k_spmm3<false, true><<<NB_ROW4, 256, 0, stream>>>(
        rp, csr, pack, dis, xa, cwt + 8192, conv_b + 128, nullptr, lin_W, lin_b, y);

    k_out<<<(NL + 255) / 256, 256, 0, stream>>>(y, lsrc, ldst, out);
}

// Round 12
// 224.001 us; speedup vs baseline: 1.1879x; 1.1879x over previous
//
#include <hip/hip_runtime.h>
#include <hip/hip_fp16.h>
#include <math.h>

#define N_DRUG 20000
#define N_PROT 30000
#define NN (N_DRUG + N_PROT)
#define F_DRUG 128
#define F_PROT 256
#define H 64
#define NE 1600000
#define NL 200000

#define NB_PROJD ((N_DRUG + 127) / 128)          // 157 (128 rows/block)
#define NB_PROJP ((N_PROT + 127) / 128)          // 235
#define NB_ROW4  (NN / 4)                        // 12500 (4 rows/block; NN%4==0)
#define NBK1 256                                  // partition chunks
#define CH   ((NE + NBK1 - 1) / NBK1)            // 6250 edges/chunk
#define NB_BKT ((NN + 255) / 256)                // 196 buckets

typedef _Float16 h8 __attribute__((ext_vector_type(8)));
typedef _Float16 h4 __attribute__((ext_vector_type(4)));
typedef float f32x4 __attribute__((ext_vector_type(4)));

#define MFMA16(a, b, c) __builtin_amdgcn_mfma_f32_16x16x32_f16((a), (b), (c), 0, 0, 0)

// ---------------- weight prep ----------------
// wdt/wpt: transposed [c][k] fp16 for MFMA projections.
// cwt: conv weights ROW-major [l][f][c] fp16 (consumed by the spmm epilogue).
__global__ __launch_bounds__(256) void k_wprep(
    const float* __restrict__ Wd, const float* __restrict__ Wp,
    const float* __restrict__ cw,
    _Float16* __restrict__ wdt, _Float16* __restrict__ wpt,
    _Float16* __restrict__ cwt) {
    int i = blockIdx.x * 256 + threadIdx.x;
    if (i < 64 * F_DRUG) {
        int c = i / F_DRUG, k = i % F_DRUG;
        wdt[i] = (_Float16)Wd[k * H + c];
    }
    if (i < 64 * F_PROT) {
        int c = i / F_PROT, k = i % F_PROT;
        wpt[i] = (_Float16)Wp[k * H + c];
    }
    if (i < 3 * 64 * 64) {
        cwt[i] = (_Float16)cw[i];
    }
}

// ---------------- zero-LDS MFMA projection: out = relu(X@W + b) as fp16 [row][64] ----------------
template <int F>
__device__ __forceinline__ void proj_direct(
    const float* __restrict__ X, const _Float16* __restrict__ Wt,
    const float* __restrict__ bias, _Float16* __restrict__ out,
    int rows, int row_off, int bid) {
    int l = threadIdx.x & 63, wvi = threadIdx.x >> 6;
    int lr = l & 15, lq = l >> 4;
    int r0 = bid * 128 + wvi * 32;
    f32x4 acc[2][4];
    #pragma unroll
    for (int rt = 0; rt < 2; ++rt)
        #pragma unroll
        for (int n = 0; n < 4; ++n) acc[rt][n] = (f32x4){0.f, 0.f, 0.f, 0.f};

    for (int k0 = 0; k0 < F; k0 += 64) {
        h8 af[4][2];
        #pragma unroll
        for (int n = 0; n < 4; ++n)
            #pragma unroll
            for (int kk = 0; kk < 2; ++kk)
                af[n][kk] = *(const h8*)&Wt[(size_t)(n * 16 + lr) * F + k0 + kk * 32 + lq * 8];
        #pragma unroll
        for (int rt = 0; rt < 2; ++rt) {
            int r = r0 + rt * 16 + lr;
            int rc = (r < rows) ? r : (rows - 1);
            h8 bf[2];
            #pragma unroll
            for (int kk = 0; kk < 2; ++kk) {
                const float* xp = X + (size_t)rc * F + k0 + kk * 32 + lq * 8;
                float4 a = *(const float4*)xp;
                float4 b = *(const float4*)(xp + 4);
                h8 t;
                t[0] = (_Float16)a.x; t[1] = (_Float16)a.y;
                t[2] = (_Float16)a.z; t[3] = (_Float16)a.w;
                t[4] = (_Float16)b.x; t[5] = (_Float16)b.y;
                t[6] = (_Float16)b.z; t[7] = (_Float16)b.w;
                bf[kk] = t;
            }
            #pragma unroll
            for (int n = 0; n < 4; ++n) {
                acc[rt][n] = MFMA16(af[n][0], bf[0], acc[rt][n]);
                acc[rt][n] = MFMA16(af[n][1], bf[1], acc[rt][n]);
            }
        }
    }
    #pragma unroll
    for (int rt = 0; rt < 2; ++rt) {
        int r = r0 + rt * 16 + lr;
        if (r < rows) {
            #pragma unroll
            for (int n = 0; n < 4; ++n) {
                int c = n * 16 + lq * 4;
                float4 bv = *(const float4*)&bias[c];
                h4 hv;
                hv[0] = (_Float16)fmaxf(acc[rt][n][0] + bv.x, 0.f);
                hv[1] = (_Float16)fmaxf(acc[rt][n][1] + bv.y, 0.f);
                hv[2] = (_Float16)fmaxf(acc[rt][n][2] + bv.z, 0.f);
                hv[3] = (_Float16)fmaxf(acc[rt][n][3] + bv.w, 0.f);
                *(h4*)(out + (size_t)(row_off + r) * H + c) = hv;
            }
        }
    }
}

// ---------------- fused front: proj_drug || proj_prot || coarse bucket hist ----------------
__global__ __launch_bounds__(256) void k_front(
    const float* __restrict__ xd, const _Float16* __restrict__ wdt, const float* __restrict__ bd,
    const float* __restrict__ xp, const _Float16* __restrict__ wpt, const float* __restrict__ bp,
    const int* __restrict__ ei, unsigned* __restrict__ bhist, _Float16* __restrict__ xa) {
    __shared__ unsigned lh[256];
    int bid = blockIdx.x;
    if (bid < NB_PROJD) {
        proj_direct<F_DRUG>(xd, wdt, bd, xa, N_DRUG, 0, bid);
    } else if (bid < NB_PROJD + NB_PROJP) {
        proj_direct<F_PROT>(xp, wpt, bp, xa, N_PROT, N_DRUG, bid - NB_PROJD);
    } else {
        int blk = bid - NB_PROJD - NB_PROJP;
        int t = threadIdx.x;
        lh[t] = 0;
        __syncthreads();
        int eb = blk * CH, ee = min(NE, eb + CH);
        for (int e = eb + t; e < ee; e += 256)
            atomicAdd(&lh[((unsigned)ei[NE + e]) >> 8], 1u);
        __syncthreads();
        bhist[(size_t)t * NBK1 + blk] = lh[t];
    }
}

// ---------------- scan step A: per-bucket row sums ----------------
__global__ __launch_bounds__(256) void kA(const unsigned* __restrict__ bhist,
                                          unsigned* __restrict__ rsum) {
    __shared__ unsigned s[256];
    int j = blockIdx.x, t = threadIdx.x;
    s[t] = bhist[(size_t)j * NBK1 + t];
    __syncthreads();
    for (int off = 128; off; off >>= 1) {
        if (t < off) s[t] += s[t + off];
        __syncthreads();
    }
    if (t == 0) rsum[j] = s[0];
}

// ---------------- merged scan: bucket bases + per-bucket row scan ----------------
__global__ __launch_bounds__(256) void kC2(unsigned* __restrict__ bhist,
                                           const unsigned* __restrict__ rsum,
                                           unsigned* __restrict__ rbase) {
    __shared__ unsigned sb[256], s[256];
    int j = blockIdx.x, t = threadIdx.x;
    unsigned rc = rsum[t];
    sb[t] = rc;
    __syncthreads();
    for (int off = 1; off < 256; off <<= 1) {
        unsigned v = sb[t]; unsigned u = (t >= off) ? sb[t - off] : 0;
        __syncthreads(); sb[t] = v + u; __syncthreads();
    }
    if (j == 0) {
        rbase[t] = sb[t] - rc;
        if (t == 255) rbase[256] = sb[255];     // == NE
    }
    unsigned rb = (j > 0) ? sb[j - 1] : 0;
    unsigned c = bhist[(size_t)j * NBK1 + t];
    s[t] = c;
    __syncthreads();
    for (int off = 1; off < 256; off <<= 1) {
        unsigned v = s[t]; unsigned u = (t >= off) ? s[t - off] : 0;
        __syncthreads(); s[t] = v + u; __syncthreads();
    }
    bhist[(size_t)j * NBK1 + t] = rb + s[t] - c;
}

// ---------------- bucket partition-scatter, XCD-contiguous chunk remap ----------------
__global__ __launch_bounds__(256) void k_part(
    const int* __restrict__ ei, const unsigned* __restrict__ base,
    unsigned* __restrict__ tmp) {
    __shared__ unsigned lcur[256];
    int bid = blockIdx.x;
    int c = ((bid & 7) << 5) | (bid >> 3);
    int t = threadIdx.x;
    lcur[t] = base[(size_t)t * NBK1 + c];
    __syncthreads();
    int eb = c * CH, ee = min(NE, eb + CH);
    for (int e = eb + t; e < ee; e += 256) {
        unsigned s = (unsigned)ei[e];
        unsigned d = (unsigned)ei[NE + e];
        unsigned pos = atomicAdd(&lcur[d >> 8], 1u);
        tmp[pos] = ((d & 255u) << 16) | s;
    }
}

// ---------------- per-bucket CSR finalize: rp, dis, csr(u16) ----------------
__global__ __launch_bounds__(256) void k_csr(
    const unsigned* __restrict__ tmp, const unsigned* __restrict__ rbase,
    int* __restrict__ rp, float* __restrict__ dis,
    unsigned short* __restrict__ csr) {
    __shared__ unsigned lbin[256], lofs[256], lcur[256];
    int b = blockIdx.x, t = threadIdx.x;
    unsigned nb0 = rbase[b], nb1 = rbase[b + 1];
    lbin[t] = 0;
    __syncthreads();
    for (unsigned i = nb0 + t; i < nb1; i += 256)
        atomicAdd(&lbin[tmp[i] >> 16], 1u);
    __syncthreads();
    unsigned c = lbin[t];
    lofs[t] = c;
    __syncthreads();
    for (int off = 1; off < 256; off <<= 1) {
        unsigned v = lofs[t]; unsigned u = (t >= off) ? lofs[t - off] : 0;
        __syncthreads(); lofs[t] = v + u; __syncthreads();
    }
    unsigned r = nb0 + lofs[t] - c;
    int node = b * 256 + t;
    if (node < NN) {
        rp[node] = (int)r;
        dis[node] = rsqrtf((float)c + 1.0f);
    }
    lcur[t] = r;
    __syncthreads();
    for (unsigned i = nb0 + t; i < nb1; i += 256) {
        unsigned rec = tmp[i];
        unsigned pos = atomicAdd(&lcur[rec >> 16], 1u);
        csr[pos] = (unsigned short)(rec & 0xffffu);
    }
    if (b == 0 && t == 0) rp[NN] = NE;
}

// ---------------- SpMM + fused conv: x_out = relu((Â x_in) @ W + b) ----------------
// Edge loop = round-9 proven structure (64-wide coalesced staging, 8-deep batches,
// quarter q = lane>>4 owns edge slot, lane g = lane&15 holds features 4g..4g+3).
// Epilogue conv via shfl broadcast (no LDS, no barrier, waves independent).
template <bool FIRST, bool LAST>
__global__ __launch_bounds__(256) void k_spmm3(
    const int* __restrict__ rp, const unsigned short* __restrict__ csr,
    unsigned* __restrict__ pack, const float* __restrict__ dis,
    const _Float16* __restrict__ xin, const _Float16* __restrict__ Wl,
    const float* __restrict__ bias, _Float16* __restrict__ xout,
    const float* __restrict__ lw, const float* __restrict__ lb,
    float* __restrict__ y) {
    int lane = threadIdx.x & 63;
    int d = blockIdx.x * 4 + (threadIdx.x >> 6);   // NN % 4 == 0: always valid
    int q = lane >> 4, g = lane & 15;
    int beg = rp[d], end = rp[d + 1];
    float dd = dis[d];
    float ax = 0.f, ay = 0.f, az = 0.f, aw = 0.f;

    int n = end - beg; if (n > 64) n = 64;
    unsigned rv = 0;
    if (lane < n) {
        if (FIRST) {
            int s = csr[beg + lane];
            float w0 = dis[s] * dd;
            rv = (unsigned)s | ((unsigned)__half_as_ushort(__float2half(w0)) << 16);
            pack[beg + lane] = rv;
        } else rv = pack[beg + lane];
    }
    for (int b0 = beg; b0 < end; ) {
        int nb = b0 + 64;
        int n2 = end - nb; if (n2 > 64) n2 = 64;
        unsigned rv2 = 0;
        if (n2 > 0 && lane < n2) {
            if (FIRST) {
                int s = csr[nb + lane];
                float w0 = dis[s] * dd;
                rv2 = (unsigned)s | ((unsigned)__half_as_ushort(__float2half(w0)) << 16);
                pack[nb + lane] = rv2;
            } else rv2 = pack[nb + lane];
        }
        int nsteps = (n + 3) >> 2;
        for (int j0 = 0; j0 < nsteps; j0 += 8) {
            int m = nsteps - j0; if (m > 8) m = 8;
            h4 xv[8]; float wv[8];
            #pragma unroll
            for (int k = 0; k < 8; ++k) {
                if (k < m) {
                    unsigned r = __shfl(rv, (j0 + k) * 4 + q);   // rv==0 masks idx>=n
                    wv[k] = __half2float(__ushort_as_half((unsigned short)(r >> 16)));
                    xv[k] = *(const h4*)&xin[((r & 0xffffu) << 6) + (g << 2)];
                }
            }
            #pragma unroll
            for (int k = 0; k < 8; ++k) {
                if (k < m) {
                    ax += wv[k] * (float)xv[k][0];
                    ay += wv[k] * (float)xv[k][1];
                    az += wv[k] * (float)xv[k][2];
                    aw += wv[k] * (float)xv[k][3];
                }
            }
        }
        b0 = nb; n = n2; rv = rv2;
    }
    // reduce across quarters -> full aggregate replicated in all lanes
    ax += __shfl_xor(ax, 16); ay += __shfl_xor(ay, 16);
    az += __shfl_xor(az, 16); aw += __shfl_xor(aw, 16);
    ax += __shfl_xor(ax, 32); ay += __shfl_xor(ay, 32);
    az += __shfl_xor(az, 32); aw += __shfl_xor(aw, 32);
    // self term
    h4 xs = *(const h4*)&xin[((unsigned)d << 6) + (g << 2)];
    float sn = dd * dd;
    ax += sn * (float)xs[0]; ay += sn * (float)xs[1];
    az += sn * (float)xs[2]; aw += sn * (float)xs[3];

    // fused conv: lane (q,g) accumulates cols 4g..4g+3 over f in [16q, 16q+16)
    // agg[4j..4j+3] lives (replicated) in lane j (quarter 0 copy used).
    float o0 = 0.f, o1 = 0.f, o2 = 0.f, o3 = 0.f;
    #pragma unroll
    for (int i = 0; i < 4; ++i) {
        int grp = 4 * q + i;                      // feature group: f = 4*grp..4*grp+3
        float b0 = __shfl(ax, grp);
        float b1 = __shfl(ay, grp);
        float b2 = __shfl(az, grp);
        float b3 = __shfl(aw, grp);
        const _Float16* wp = Wl + (size_t)(4 * grp) * 64 + (g << 2);
        h4 w0 = *(const h4*)(wp);
        h4 w1 = *(const h4*)(wp + 64);
        h4 w2 = *(const h4*)(wp + 128);
        h4 w3 = *(const h4*)(wp + 192);
        o0 += b0 * (float)w0[0] + b1 * (float)w1[0] + b2 * (float)w2[0] + b3 * (float)w3[0];
        o1 += b0 * (float)w0[1] + b1 * (float)w1[1] + b2 * (float)w2[1] + b3 * (float)w3[1];
        o2 += b0 * (float)w0[2] + b1 * (float)w1[2] + b2 * (float)w2[2] + b3 * (float)w3[2];
        o3 += b0 * (float)w0[3] + b1 * (float)w1[3] + b2 * (float)w2[3] + b3 * (float)w3[3];
    }
    // reduce the f-partials across quarters
    o0 += __shfl_xor(o0, 16); o1 += __shfl_xor(o1, 16);
    o2 += __shfl_xor(o2, 16); o3 += __shfl_xor(o3, 16);
    o0 += __shfl_xor(o0, 32); o1 += __shfl_xor(o1, 32);
    o2 += __shfl_xor(o2, 32); o3 += __shfl_xor(o3, 32);

    float4 bv = *(const float4*)&bias[g << 2];
    float vx = fmaxf(o0 + bv.x, 0.f);
    float vy = fmaxf(o1 + bv.y, 0.f);
    float vz = fmaxf(o2 + bv.z, 0.f);
    float vw = fmaxf(o3 + bv.w, 0.f);
    if (LAST) {
        float4 lv = *(const float4*)&lw[g << 2];
        float tt = vx * lv.x + vy * lv.y + vz * lv.z + vw * lv.w;
        tt += __shfl_xor(tt, 1); tt += __shfl_xor(tt, 2);
        tt += __shfl_xor(tt, 4); tt += __shfl_xor(tt, 8);
        if (lane == 0) y[d] = tt + lb[0];
    } else if (q == 0) {
        h4 hv;
        hv[0] = (_Float16)vx; hv[1] = (_Float16)vy;
        hv[2] = (_Float16)vz; hv[3] = (_Float16)vw;
        *(h4*)(xout + ((size_t)d << 6) + (g << 2)) = hv;
    }
}

// ---------------- edge scoring: sigmoid(y[src]*y[dst]) ----------------
__global__ void k_out(const float* __restrict__ y, const int* __restrict__ ls,
                      const int* __restrict__ ld, float* __restrict__ out) {
    int e = blockIdx.x * blockDim.x + threadIdx.x;
    if (e < NL) {
        float z = y[ls[e]] * y[ld[e]];
        out[e] = 1.f / (1.f + __expf(-z));
    }
}

static inline size_t up256(size_t x) { return (x + 255) & ~(size_t)255; }

extern "C" void kernel_launch(void* const* d_in, const int* in_sizes, int n_in,
                              void* d_out, int out_size, void* d_ws, size_t ws_size,
                              hipStream_t stream) {
    const float* x_drug = (const float*)d_in[0];
    const float* x_prot = (const float*)d_in[1];
    const float* W_drug = (const float*)d_in[2];
    const float* b_drug = (const float*)d_in[3];
    const float* W_prot = (const float*)d_in[4];
    const float* b_prot = (const float*)d_in[5];
    const float* conv_W = (const float*)d_in[6];
    const float* conv_b = (const float*)d_in[7];
    const float* lin_W  = (const float*)d_in[8];
    const float* lin_b  = (const float*)d_in[9];
    const int*   ei     = (const int*)d_in[10];
    const int*   lsrc   = (const int*)d_in[11];
    const int*   ldst   = (const int*)d_in[12];
    float* out = (float*)d_out;

    char* w = (char*)d_ws;
    size_t off = 0;
    unsigned* bhist = (unsigned*)(w + off); off = up256(off + (size_t)256 * NBK1 * 4);
    unsigned* rsum  = (unsigned*)(w + off); off = up256(off + 256 * 4);
    unsigned* rbase = (unsigned*)(w + off); off = up256(off + 257 * 4);
    unsigned* tmp   = (unsigned*)(w + off); off = up256(off + (size_t)NE * 4);
    unsigned short* csr = (unsigned short*)(w + off); off = up256(off + (size_t)NE * 2);
    unsigned* pack  = (unsigned*)(w + off); off = up256(off + (size_t)NE * 4);
    int*    rp   = (int*)(w + off);    off = up256(off + (size_t)(NN + 1) * 4);
    float*  dis  = (float*)(w + off);  off = up256(off + (size_t)NN * 4);
    _Float16* xa = (_Float16*)(w + off); off = up256(off + (size_t)NN * H * 2);
    _Float16* xb = (_Float16*)(w + off); off = up256(off + (size_t)NN * H * 2);
    float*  y    = (float*)(w + off);  off = up256(off + (size_t)NN * 4);
    _Float16* wdt = (_Float16*)(w + off); off = up256(off + (size_t)64 * F_DRUG * 2);
    _Float16* wpt = (_Float16*)(w + off); off = up256(off + (size_t)64 * F_PROT * 2);
    _Float16* cwt = (_Float16*)(w + off); off = up256(off + (size_t)3 * 64 * 64 * 2);

    k_wprep<<<64, 256, 0, stream>>>(W_drug, W_prot, conv_W, wdt, wpt, cwt);

    // proj_drug || proj_prot || coarse hist
    k_front<<<NB_PROJD + NB_PROJP + NBK1, 256, 0, stream>>>(
        x_drug, wdt, b_drug, x_prot, wpt, b_prot, ei, bhist, xa);

    kA<<<256, 256, 0, stream>>>(bhist, rsum);
    kC2<<<256, 256, 0, stream>>>(bhist, rsum, rbase);

    // bucket partition-scatter (XCD-contiguous chunks)
    k_part<<<NBK1, 256, 0, stream>>>(ei, bhist, tmp);

    // per-bucket CSR finalize (rp, dis, u16 src)
    k_csr<<<NB_BKT, 256, 0, stream>>>(tmp, rbase, rp, dis, csr);

    // layer 0: xa -> xb (builds pack, conv fused)
    k_spmm3<true, false><<<NB_ROW4, 256, 0, stream>>>(
        rp, csr, pack, dis, xa, cwt, conv_b, xb, nullptr, nullptr, nullptr);
    // layer 1: xb -> xa
    k_spmm3<false, false><<<NB_ROW4, 256, 0, stream>>>(
        rp, csr, pack, dis, xb, cwt + 4096, conv_b + 64, xa, nullptr, nullptr, nullptr);
    // layer 2: xa -> y (fused lin head)
    k_spmm3<false, true><<<NB_ROW4, 256, 0, stream>>>(
        rp, csr, pack, dis, xa, cwt + 8192, conv_b + 128, nullptr, lin_W, lin_b, y);

    k_out<<<(NL + 255) / 256, 256, 0, stream>>>(y, lsrc, ldst, out);
}

// Round 13
// 185.338 us; speedup vs baseline: 1.4357x; 1.2086x over previous
//
#include <hip/hip_runtime.h>
#include <hip/hip_fp16.h>
#include <math.h>

#define N_DRUG 20000
#define N_PROT 30000
#define NN (N_DRUG + N_PROT)
#define F_DRUG 128
#define F_PROT 256
#define H 64
#define NE 1600000
#define NL 200000

#define NB_PROJD ((N_DRUG + 127) / 128)          // 157 (128 rows/block)
#define NB_PROJP ((N_PROT + 127) / 128)          // 235
#define NB_CONV  ((NN + 255) / 256)              // 196 (256 rows/block)
#define NB_ROW4  (NN / 4)                        // 12500 (4 rows/block; NN%4==0)
#define NBK1 256                                  // partition chunks
#define CH   ((NE + NBK1 - 1) / NBK1)            // 6250 edges/chunk
#define NB_BKT ((NN + 255) / 256)                // 196 buckets

typedef _Float16 h8 __attribute__((ext_vector_type(8)));
typedef _Float16 h4 __attribute__((ext_vector_type(4)));
typedef float f32x4 __attribute__((ext_vector_type(4)));

#define MFMA16(a, b, c) __builtin_amdgcn_mfma_f32_16x16x32_f16((a), (b), (c), 0, 0, 0)

// ---------------- weight prep: transpose + fp16 ([c][k] layout) ----------------
__global__ __launch_bounds__(256) void k_wprep(
    const float* __restrict__ Wd, const float* __restrict__ Wp,
    const float* __restrict__ cw,
    _Float16* __restrict__ wdt, _Float16* __restrict__ wpt,
    _Float16* __restrict__ cwt) {
    int i = blockIdx.x * 256 + threadIdx.x;
    if (i < 64 * F_DRUG) {
        int c = i / F_DRUG, k = i % F_DRUG;
        wdt[i] = (_Float16)Wd[k * H + c];
    }
    if (i < 64 * F_PROT) {
        int c = i / F_PROT, k = i % F_PROT;
        wpt[i] = (_Float16)Wp[k * H + c];
    }
    if (i < 3 * 64 * 64) {
        int l = i >> 12, r = i & 4095;
        int c = r >> 6, k = r & 63;
        cwt[i] = (_Float16)cw[(l << 12) + k * H + c];
    }
}

// ---------------- zero-LDS MFMA projection: out = relu(X@W + b) as fp16 [row][64] ----------------
template <int F>
__device__ __forceinline__ void proj_direct(
    const float* __restrict__ X, const _Float16* __restrict__ Wt,
    const float* __restrict__ bias, _Float16* __restrict__ out,
    int rows, int row_off, int bid) {
    int l = threadIdx.x & 63, wvi = threadIdx.x >> 6;
    int lr = l & 15, lq = l >> 4;
    int r0 = bid * 128 + wvi * 32;
    f32x4 acc[2][4];
    #pragma unroll
    for (int rt = 0; rt < 2; ++rt)
        #pragma unroll
        for (int n = 0; n < 4; ++n) acc[rt][n] = (f32x4){0.f, 0.f, 0.f, 0.f};

    for (int k0 = 0; k0 < F; k0 += 64) {
        h8 af[4][2];
        #pragma unroll
        for (int n = 0; n < 4; ++n)
            #pragma unroll
            for (int kk = 0; kk < 2; ++kk)
                af[n][kk] = *(const h8*)&Wt[(size_t)(n * 16 + lr) * F + k0 + kk * 32 + lq * 8];
        #pragma unroll
        for (int rt = 0; rt < 2; ++rt) {
            int r = r0 + rt * 16 + lr;
            int rc = (r < rows) ? r : (rows - 1);
            h8 bf[2];
            #pragma unroll
            for (int kk = 0; kk < 2; ++kk) {
                const float* xp = X + (size_t)rc * F + k0 + kk * 32 + lq * 8;
                float4 a = *(const float4*)xp;
                float4 b = *(const float4*)(xp + 4);
                h8 t;
                t[0] = (_Float16)a.x; t[1] = (_Float16)a.y;
                t[2] = (_Float16)a.z; t[3] = (_Float16)a.w;
                t[4] = (_Float16)b.x; t[5] = (_Float16)b.y;
                t[6] = (_Float16)b.z; t[7] = (_Float16)b.w;
                bf[kk] = t;
            }
            #pragma unroll
            for (int n = 0; n < 4; ++n) {
                acc[rt][n] = MFMA16(af[n][0], bf[0], acc[rt][n]);
                acc[rt][n] = MFMA16(af[n][1], bf[1], acc[rt][n]);
            }
        }
    }
    #pragma unroll
    for (int rt = 0; rt < 2; ++rt) {
        int r = r0 + rt * 16 + lr;
        if (r < rows) {
            #pragma unroll
            for (int n = 0; n < 4; ++n) {
                int c = n * 16 + lq * 4;
                float4 bv = *(const float4*)&bias[c];
                h4 hv;
                hv[0] = (_Float16)fmaxf(acc[rt][n][0] + bv.x, 0.f);
                hv[1] = (_Float16)fmaxf(acc[rt][n][1] + bv.y, 0.f);
                hv[2] = (_Float16)fmaxf(acc[rt][n][2] + bv.z, 0.f);
                hv[3] = (_Float16)fmaxf(acc[rt][n][3] + bv.w, 0.f);
                *(h4*)(out + (size_t)(row_off + r) * H + c) = hv;
            }
        }
    }
}

// ---------------- zero-LDS MFMA conv: xw = x @ Wl (fp16 in/out, fp32 acc) ----------------
__device__ __forceinline__ void conv_direct(
    const _Float16* __restrict__ xh, const _Float16* __restrict__ Wt,
    _Float16* __restrict__ xout, int bid) {
    int l = threadIdx.x & 63, wvi = threadIdx.x >> 6;
    int lr = l & 15, lq = l >> 4;
    h8 af[4][2];
    #pragma unroll
    for (int n = 0; n < 4; ++n)
        #pragma unroll
        for (int kk = 0; kk < 2; ++kk)
            af[n][kk] = *(const h8*)&Wt[(size_t)(n * 16 + lr) * 64 + kk * 32 + lq * 8];
    int r0 = bid * 256 + wvi * 64;
    #pragma unroll
    for (int rt = 0; rt < 4; ++rt) {
        int r = r0 + rt * 16 + lr;
        int rc = (r < NN) ? r : (NN - 1);
        h8 bf0 = *(const h8*)&xh[(size_t)rc * H + lq * 8];
        h8 bf1 = *(const h8*)&xh[(size_t)rc * H + 32 + lq * 8];
        f32x4 a[4];
        #pragma unroll
        for (int n = 0; n < 4; ++n) {
            a[n] = (f32x4){0.f, 0.f, 0.f, 0.f};
            a[n] = MFMA16(af[n][0], bf0, a[n]);
            a[n] = MFMA16(af[n][1], bf1, a[n]);
        }
        if (r < NN) {
            #pragma unroll
            for (int n = 0; n < 4; ++n) {
                int c = n * 16 + lq * 4;
                h4 hv;
                hv[0] = (_Float16)a[n][0]; hv[1] = (_Float16)a[n][1];
                hv[2] = (_Float16)a[n][2]; hv[3] = (_Float16)a[n][3];
                *(h4*)(xout + (size_t)r * H + c) = hv;
            }
        }
    }
}

// ---------------- fused front: proj_drug || proj_prot || coarse bucket hist ----------------
__global__ __launch_bounds__(256) void k_front(
    const float* __restrict__ xd, const _Float16* __restrict__ wdt, const float* __restrict__ bd,
    const float* __restrict__ xp, const _Float16* __restrict__ wpt, const float* __restrict__ bp,
    const int* __restrict__ ei, unsigned* __restrict__ bhist, _Float16* __restrict__ xa) {
    __shared__ unsigned lh[256];
    int bid = blockIdx.x;
    if (bid < NB_PROJD) {
        proj_direct<F_DRUG>(xd, wdt, bd, xa, N_DRUG, 0, bid);
    } else if (bid < NB_PROJD + NB_PROJP) {
        proj_direct<F_PROT>(xp, wpt, bp, xa, N_PROT, N_DRUG, bid - NB_PROJD);
    } else {
        int blk = bid - NB_PROJD - NB_PROJP;
        int t = threadIdx.x;
        lh[t] = 0;
        __syncthreads();
        int eb = blk * CH, ee = min(NE, eb + CH);
        for (int e = eb + t; e < ee; e += 256)
            atomicAdd(&lh[((unsigned)ei[NE + e]) >> 8], 1u);
        __syncthreads();
        bhist[(size_t)t * NBK1 + blk] = lh[t];
    }
}

// ---------------- scan step A: per-bucket row sums ----------------
__global__ __launch_bounds__(256) void kA(const unsigned* __restrict__ bhist,
                                          unsigned* __restrict__ rsum) {
    __shared__ unsigned s[256];
    int j = blockIdx.x, t = threadIdx.x;
    s[t] = bhist[(size_t)j * NBK1 + t];
    __syncthreads();
    for (int off = 128; off; off >>= 1) {
        if (t < off) s[t] += s[t + off];
        __syncthreads();
    }
    if (t == 0) rsum[j] = s[0];
}

// ---------------- merged scan: bucket bases + per-bucket row scan ----------------
__global__ __launch_bounds__(256) void kC2(unsigned* __restrict__ bhist,
                                           const unsigned* __restrict__ rsum,
                                           unsigned* __restrict__ rbase) {
    __shared__ unsigned sb[256], s[256];
    int j = blockIdx.x, t = threadIdx.x;
    unsigned rc = rsum[t];
    sb[t] = rc;
    __syncthreads();
    for (int off = 1; off < 256; off <<= 1) {
        unsigned v = sb[t]; unsigned u = (t >= off) ? sb[t - off] : 0;
        __syncthreads(); sb[t] = v + u; __syncthreads();
    }
    if (j == 0) {
        rbase[t] = sb[t] - rc;
        if (t == 255) rbase[256] = sb[255];     // == NE
    }
    unsigned rb = (j > 0) ? sb[j - 1] : 0;
    unsigned c = bhist[(size_t)j * NBK1 + t];
    s[t] = c;
    __syncthreads();
    for (int off = 1; off < 256; off <<= 1) {
        unsigned v = s[t]; unsigned u = (t >= off) ? s[t - off] : 0;
        __syncthreads(); s[t] = v + u; __syncthreads();
    }
    bhist[(size_t)j * NBK1 + t] = rb + s[t] - c;
}

// ---------------- bucket partition-scatter, XCD-contiguous chunk remap ----------------
__global__ __launch_bounds__(256) void k_part(
    const int* __restrict__ ei, const unsigned* __restrict__ base,
    unsigned* __restrict__ tmp) {
    __shared__ unsigned lcur[256];
    int bid = blockIdx.x;
    int c = ((bid & 7) << 5) | (bid >> 3);
    int t = threadIdx.x;
    lcur[t] = base[(size_t)t * NBK1 + c];
    __syncthreads();
    int eb = c * CH, ee = min(NE, eb + CH);
    for (int e = eb + t; e < ee; e += 256) {
        unsigned s = (unsigned)ei[e];
        unsigned d = (unsigned)ei[NE + e];
        unsigned pos = atomicAdd(&lcur[d >> 8], 1u);
        tmp[pos] = ((d & 255u) << 16) | s;
    }
}

// ---------------- per-bucket CSR finalize: rp, dis, csr(u16) ----------------
__global__ __launch_bounds__(256) void k_csr(
    const unsigned* __restrict__ tmp, const unsigned* __restrict__ rbase,
    int* __restrict__ rp, float* __restrict__ dis,
    unsigned short* __restrict__ csr) {
    __shared__ unsigned lbin[256], lofs[256], lcur[256];
    int b = blockIdx.x, t = threadIdx.x;
    unsigned nb0 = rbase[b], nb1 = rbase[b + 1];
    lbin[t] = 0;
    __syncthreads();
    for (unsigned i = nb0 + t; i < nb1; i += 256)
        atomicAdd(&lbin[tmp[i] >> 16], 1u);
    __syncthreads();
    unsigned c = lbin[t];
    lofs[t] = c;
    __syncthreads();
    for (int off = 1; off < 256; off <<= 1) {
        unsigned v = lofs[t]; unsigned u = (t >= off) ? lofs[t - off] : 0;
        __syncthreads(); lofs[t] = v + u; __syncthreads();
    }
    unsigned r = nb0 + lofs[t] - c;
    int node = b * 256 + t;
    if (node < NN) {
        rp[node] = (int)r;
        dis[node] = rsqrtf((float)c + 1.0f);
    }
    lcur[t] = r;
    __syncthreads();
    for (unsigned i = nb0 + t; i < nb1; i += 256) {
        unsigned rec = tmp[i];
        unsigned pos = atomicAdd(&lcur[rec >> 16], 1u);
        csr[pos] = (unsigned short)(rec & 0xffffu);
    }
    if (b == 0 && t == 0) rp[NN] = NE;
}

// ---------------- standalone conv (layers 1,2) ----------------
__global__ __launch_bounds__(256) void k_conv(
    const _Float16* __restrict__ X, const _Float16* __restrict__ Wt,
    _Float16* __restrict__ out) {
    conv_direct(X, Wt, out, blockIdx.x);
}

// ---------------- SpMM oct-structure: 8 edge slots/wave, h8 (16B) per lane ----------------
// oct o = lane>>3 owns edge slot; g = lane&7 holds features 8g..8g+7.
// Per 8 edges: 1 shfl + 1 h8 load + 8 fma per lane (2x fewer VMEM instr than h4 scheme).
// FIRST: builds pack[] = src | f16(dis_s*dis_d)<<16.
template <bool FIRST, bool LAST>
__global__ __launch_bounds__(256) void k_spmm4(
    const int* __restrict__ rp, const unsigned short* __restrict__ csr,
    unsigned* __restrict__ pack, const float* __restrict__ dis,
    const _Float16* __restrict__ xin,
    const float* __restrict__ bias, _Float16* __restrict__ xout,
    const float* __restrict__ lw, const float* __restrict__ lb,
    float* __restrict__ y) {
    int lane = threadIdx.x & 63;
    int d = blockIdx.x * 4 + (threadIdx.x >> 6);   // NN % 4 == 0
    int o = lane >> 3, g = lane & 7;
    int beg = rp[d], end = rp[d + 1];
    float dd = dis[d];
    float acc[8];
    #pragma unroll
    for (int i = 0; i < 8; ++i) acc[i] = 0.f;

    int n = end - beg; if (n > 64) n = 64;
    unsigned rv = 0;
    if (lane < n) {
        if (FIRST) {
            int s = csr[beg + lane];
            float w0 = dis[s] * dd;
            rv = (unsigned)s | ((unsigned)__half_as_ushort(__float2half(w0)) << 16);
            pack[beg + lane] = rv;
        } else rv = pack[beg + lane];
    }
    for (int b0 = beg; b0 < end; ) {
        int nb = b0 + 64;
        int n2 = end - nb; if (n2 > 64) n2 = 64;
        unsigned rv2 = 0;
        if (n2 > 0 && lane < n2) {
            if (FIRST) {
                int s = csr[nb + lane];
                float w0 = dis[s] * dd;
                rv2 = (unsigned)s | ((unsigned)__half_as_ushort(__float2half(w0)) << 16);
                pack[nb + lane] = rv2;
            } else rv2 = pack[nb + lane];
        }
        int nsteps = (n + 7) >> 3;                 // <= 8
        #pragma unroll 4
        for (int jj = 0; jj < nsteps; ++jj) {
            unsigned r = __shfl(rv, jj * 8 + o);   // rv==0 masks idx>=n (w==0)
            float w = __half2float(__ushort_as_half((unsigned short)(r >> 16)));
            h8 xv = *(const h8*)&xin[((r & 0xffffu) << 6) + (g << 3)];
            #pragma unroll
            for (int i = 0; i < 8; ++i) acc[i] += w * (float)xv[i];
        }
        b0 = nb; n = n2; rv = rv2;
    }
    // reduce across the 8 octs -> full sums replicated
    #pragma unroll
    for (int off = 8; off < 64; off <<= 1)
        #pragma unroll
        for (int i = 0; i < 8; ++i) acc[i] += __shfl_xor(acc[i], off);
    // self term
    h8 xs = *(const h8*)&xin[((unsigned)d << 6) + (g << 3)];
    float sn = dd * dd;
    #pragma unroll
    for (int i = 0; i < 8; ++i) acc[i] += sn * (float)xs[i];

    if (LAST) {
        float4 l0 = *(const float4*)&lw[g << 3];
        float4 l1 = *(const float4*)&lw[(g << 3) + 4];
        float t = acc[0] * l0.x + acc[1] * l0.y + acc[2] * l0.z + acc[3] * l0.w
                + acc[4] * l1.x + acc[5] * l1.y + acc[6] * l1.z + acc[7] * l1.w;
        t += __shfl_xor(t, 1); t += __shfl_xor(t, 2); t += __shfl_xor(t, 4);
        if (lane == 0) y[d] = t + lb[0];
    } else if (o == 0) {
        float4 b0 = *(const float4*)&bias[g << 3];
        float4 b1 = *(const float4*)&bias[(g << 3) + 4];
        h8 hv;
        hv[0] = (_Float16)fmaxf(acc[0] + b0.x, 0.f);
        hv[1] = (_Float16)fmaxf(acc[1] + b0.y, 0.f);
        hv[2] = (_Float16)fmaxf(acc[2] + b0.z, 0.f);
        hv[3] = (_Float16)fmaxf(acc[3] + b0.w, 0.f);
        hv[4] = (_Float16)fmaxf(acc[4] + b1.x, 0.f);
        hv[5] = (_Float16)fmaxf(acc[5] + b1.y, 0.f);
        hv[6] = (_Float16)fmaxf(acc[6] + b1.z, 0.f);
        hv[7] = (_Float16)fmaxf(acc[7] + b1.w, 0.f);
        *(h8*)(xout + ((size_t)d << 6) + (g << 3)) = hv;
    }
}

// ---------------- edge scoring: sigmoid(y[src]*y[dst]) ----------------
__global__ void k_out(const float* __restrict__ y, const int* __restrict__ ls,
                      const int* __restrict__ ld, float* __restrict__ out) {
    int e = blockIdx.x * blockDim.x + threadIdx.x;
    if (e < NL) {
        float z = y[ls[e]] * y[ld[e]];
        out[e] = 1.f / (1.f + __expf(-z));
    }
}

static inline size_t up256(size_t x) { return (x + 255) & ~(size_t)255; }

extern "C" void kernel_launch(void* const* d_in, const int* in_sizes, int n_in,
                              void* d_out, int out_size, void* d_ws, size_t ws_size,
                              hipStream_t stream) {
    const float* x_drug = (const float*)d_in[0];
    const float* x_prot = (const float*)d_in[1];
    const float* W_drug = (const float*)d_in[2];
    const float* b_drug = (const float*)d_in[3];
    const float* W_prot = (const float*)d_in[4];
    const float* b_prot = (const float*)d_in[5];
    const float* conv_W = (const float*)d_in[6];
    const float* conv_b = (const float*)d_in[7];
    const float* lin_W  = (const float*)d_in[8];
    const float* lin_b  = (const float*)d_in[9];
    const int*   ei     = (const int*)d_in[10];
    const int*   lsrc   = (const int*)d_in[11];
    const int*   ldst   = (const int*)d_in[12];
    float* out = (float*)d_out;

    char* w = (char*)d_ws;
    size_t off = 0;
    unsigned* bhist = (unsigned*)(w + off); off = up256(off + (size_t)256 * NBK1 * 4);
    unsigned* rsum  = (unsigned*)(w + off); off = up256(off + 256 * 4);
    unsigned* rbase = (unsigned*)(w + off); off = up256(off + 257 * 4);
    unsigned* tmp   = (unsigned*)(w + off); off = up256(off + (size_t)NE * 4);
    unsigned short* csr = (unsigned short*)(w + off); off = up256(off + (size_t)NE * 2);
    unsigned* pack  = (unsigned*)(w + off); off = up256(off + (size_t)NE * 4);
    int*    rp   = (int*)(w + off);    off = up256(off + (size_t)(NN + 1) * 4);
    float*  dis  = (float*)(w + off);  off = up256(off + (size_t)NN * 4);
    _Float16* xa = (_Float16*)(w + off); off = up256(off + (size_t)NN * H * 2);
    _Float16* xb = (_Float16*)(w + off); off = up256(off + (size_t)NN * H * 2);
    _Float16* xw = (_Float16*)(w + off); off = up256(off + (size_t)NN * H * 2);
    float*  y    = (float*)(w + off);  off = up256(off + (size_t)NN * 4);
    _Float16* wdt = (_Float16*)(w + off); off = up256(off + (size_t)64 * F_DRUG * 2);
    _Float16* wpt = (_Float16*)(w + off); off = up256(off + (size_t)64 * F_PROT * 2);
    _Float16* cwt = (_Float16*)(w + off); off = up256(off + (size_t)3 * 64 * 64 * 2);

    k_wprep<<<64, 256, 0, stream>>>(W_drug, W_prot, conv_W, wdt, wpt, cwt);

    // proj_drug || proj_prot || coarse hist
    k_front<<<NB_PROJD + NB_PROJP + NBK1, 256, 0, stream>>>(
        x_drug, wdt, b_drug, x_prot, wpt, b_prot, ei, bhist, xa);

    kA<<<256, 256, 0, stream>>>(bhist, rsum);
    kC2<<<256, 256, 0, stream>>>(bhist, rsum, rbase);

    // bucket partition-scatter (XCD-contiguous chunks)
    k_part<<<NBK1, 256, 0, stream>>>(ei, bhist, tmp);

    // per-bucket CSR finalize (rp, dis, u16 src)
    k_csr<<<NB_BKT, 256, 0, stream>>>(tmp, rbase, rp, dis, csr);

    // layer 0: conv0(xa)->xw, spmm(xw)->xb   (conv0 fused nowhere: standalone MFMA)
    k_conv<<<NB_CONV, 256, 0, stream>>>(xa, cwt, xw);
    k_spmm4<true, false><<<NB_ROW4, 256, 0, stream>>>(
        rp, csr, pack, dis, xw, conv_b, xb, nullptr, nullptr, nullptr);
    // layer 1
    k_conv<<<NB_CONV, 256, 0, stream>>>(xb, cwt + 4096, xw);
    k_spmm4<false, false><<<NB_ROW4, 256, 0, stream>>>(
        rp, csr, pack, dis, xw, conv_b + 64, xa, nullptr, nullptr, nullptr);
    // layer 2 (fused lin head)
    k_conv<<<NB_CONV, 256, 0, stream>>>(xa, cwt + 8192, xw);
    k_spmm4<false, true><<<NB_ROW4, 256, 0, stream>>>(
        rp, csr, pack, dis, xw, conv_b + 128, nullptr, lin_W, lin_b, y);

    k_out<<<(NL + 255) / 256, 256, 0, stream>>>(y, lsrc, ldst, out);
}

// Round 14
// 181.998 us; speedup vs baseline: 1.4621x; 1.0184x over previous
//
#include <hip/hip_runtime.h>
#include <hip/hip_fp16.h>
#include <math.h>

#define N_DRUG 20000
#define N_PROT 30000
#define NN (N_DRUG + N_PROT)
#define F_DRUG 128
#define F_PROT 256
#define H 64
#define NE 1600000
#define NL 200000

#define NB_PROJD ((N_DRUG + 255) / 256)          // 79  (256 rows/block)
#define NB_PROJP ((N_PROT + 255) / 256)          // 118
#define NB_CONV  ((NN + 255) / 256)              // 196 (256 rows/block)
#define NB_ROW4  (NN / 4)                        // 12500 (4 rows/block; NN%4==0)
#define NBK1 256                                  // partition chunks
#define CH   ((NE + NBK1 - 1) / NBK1)            // 6250 edges/chunk
#define NB_BKT ((NN + 255) / 256)                // 196 buckets

typedef _Float16 h8 __attribute__((ext_vector_type(8)));
typedef _Float16 h4 __attribute__((ext_vector_type(4)));
typedef float f32x4 __attribute__((ext_vector_type(4)));

#define MFMA16(a, b, c) __builtin_amdgcn_mfma_f32_16x16x32_f16((a), (b), (c), 0, 0, 0)

// ---------------- weight prep: transpose + fp16 ([c][k] layout) ----------------
__global__ __launch_bounds__(256) void k_wprep(
    const float* __restrict__ Wd, const float* __restrict__ Wp,
    const float* __restrict__ cw,
    _Float16* __restrict__ wdt, _Float16* __restrict__ wpt,
    _Float16* __restrict__ cwt) {
    int i = blockIdx.x * 256 + threadIdx.x;
    if (i < 64 * F_DRUG) {
        int c = i / F_DRUG, k = i % F_DRUG;
        wdt[i] = (_Float16)Wd[k * H + c];
    }
    if (i < 64 * F_PROT) {
        int c = i / F_PROT, k = i % F_PROT;
        wpt[i] = (_Float16)Wp[k * H + c];
    }
    if (i < 3 * 64 * 64) {
        int l = i >> 12, r = i & 4095;
        int c = r >> 6, k = r & 63;
        cwt[i] = (_Float16)cw[(l << 12) + k * H + c];
    }
}

// ---------------- zero-LDS MFMA projection: out = relu(X@W + b), 64 rows/wave ----------------
template <int F>
__device__ __forceinline__ void proj_direct(
    const float* __restrict__ X, const _Float16* __restrict__ Wt,
    const float* __restrict__ bias, _Float16* __restrict__ out,
    int rows, int row_off, int bid) {
    int l = threadIdx.x & 63, wvi = threadIdx.x >> 6;
    int lr = l & 15, lq = l >> 4;
    int r0 = bid * 256 + wvi * 64;
    f32x4 acc[4][4];
    #pragma unroll
    for (int rt = 0; rt < 4; ++rt)
        #pragma unroll
        for (int n = 0; n < 4; ++n) acc[rt][n] = (f32x4){0.f, 0.f, 0.f, 0.f};

    for (int k0 = 0; k0 < F; k0 += 64) {
        h8 af[4][2];
        #pragma unroll
        for (int n = 0; n < 4; ++n)
            #pragma unroll
            for (int kk = 0; kk < 2; ++kk)
                af[n][kk] = *(const h8*)&Wt[(size_t)(n * 16 + lr) * F + k0 + kk * 32 + lq * 8];
        #pragma unroll
        for (int rt = 0; rt < 4; ++rt) {
            int r = r0 + rt * 16 + lr;
            int rc = (r < rows) ? r : (rows - 1);
            h8 bf[2];
            #pragma unroll
            for (int kk = 0; kk < 2; ++kk) {
                const float* xp = X + (size_t)rc * F + k0 + kk * 32 + lq * 8;
                float4 a = *(const float4*)xp;
                float4 b = *(const float4*)(xp + 4);
                h8 t;
                t[0] = (_Float16)a.x; t[1] = (_Float16)a.y;
                t[2] = (_Float16)a.z; t[3] = (_Float16)a.w;
                t[4] = (_Float16)b.x; t[5] = (_Float16)b.y;
                t[6] = (_Float16)b.z; t[7] = (_Float16)b.w;
                bf[kk] = t;
            }
            #pragma unroll
            for (int n = 0; n < 4; ++n) {
                acc[rt][n] = MFMA16(af[n][0], bf[0], acc[rt][n]);
                acc[rt][n] = MFMA16(af[n][1], bf[1], acc[rt][n]);
            }
        }
    }
    #pragma unroll
    for (int rt = 0; rt < 4; ++rt) {
        int r = r0 + rt * 16 + lr;
        if (r < rows) {
            #pragma unroll
            for (int n = 0; n < 4; ++n) {
                int c = n * 16 + lq * 4;
                float4 bv = *(const float4*)&bias[c];
                h4 hv;
                hv[0] = (_Float16)fmaxf(acc[rt][n][0] + bv.x, 0.f);
                hv[1] = (_Float16)fmaxf(acc[rt][n][1] + bv.y, 0.f);
                hv[2] = (_Float16)fmaxf(acc[rt][n][2] + bv.z, 0.f);
                hv[3] = (_Float16)fmaxf(acc[rt][n][3] + bv.w, 0.f);
                *(h4*)(out + (size_t)(row_off + r) * H + c) = hv;
            }
        }
    }
}

// ---------------- zero-LDS MFMA conv: xw = x @ Wl (fp16 in/out, fp32 acc) ----------------
__device__ __forceinline__ void conv_direct(
    const _Float16* __restrict__ xh, const _Float16* __restrict__ Wt,
    _Float16* __restrict__ xout, int bid) {
    int l = threadIdx.x & 63, wvi = threadIdx.x >> 6;
    int lr = l & 15, lq = l >> 4;
    h8 af[4][2];
    #pragma unroll
    for (int n = 0; n < 4; ++n)
        #pragma unroll
        for (int kk = 0; kk < 2; ++kk)
            af[n][kk] = *(const h8*)&Wt[(size_t)(n * 16 + lr) * 64 + kk * 32 + lq * 8];
    int r0 = bid * 256 + wvi * 64;
    #pragma unroll
    for (int rt = 0; rt < 4; ++rt) {
        int r = r0 + rt * 16 + lr;
        int rc = (r < NN) ? r : (NN - 1);
        h8 bf0 = *(const h8*)&xh[(size_t)rc * H + lq * 8];
        h8 bf1 = *(const h8*)&xh[(size_t)rc * H + 32 + lq * 8];
        f32x4 a[4];
        #pragma unroll
        for (int n = 0; n < 4; ++n) {
            a[n] = (f32x4){0.f, 0.f, 0.f, 0.f};
            a[n] = MFMA16(af[n][0], bf0, a[n]);
            a[n] = MFMA16(af[n][1], bf1, a[n]);
        }
        if (r < NN) {
            #pragma unroll
            for (int n = 0; n < 4; ++n) {
                int c = n * 16 + lq * 4;
                h4 hv;
                hv[0] = (_Float16)a[n][0]; hv[1] = (_Float16)a[n][1];
                hv[2] = (_Float16)a[n][2]; hv[3] = (_Float16)a[n][3];
                *(h4*)(xout + (size_t)r * H + c) = hv;
            }
        }
    }
}

// ---------------- fused front: proj_drug || proj_prot || coarse bucket hist ----------------
__global__ __launch_bounds__(256) void k_front(
    const float* __restrict__ xd, const _Float16* __restrict__ wdt, const float* __restrict__ bd,
    const float* __restrict__ xp, const _Float16* __restrict__ wpt, const float* __restrict__ bp,
    const int* __restrict__ ei, unsigned* __restrict__ bhist, _Float16* __restrict__ xa) {
    __shared__ unsigned lh[256];
    int bid = blockIdx.x;
    if (bid < NB_PROJD) {
        proj_direct<F_DRUG>(xd, wdt, bd, xa, N_DRUG, 0, bid);
    } else if (bid < NB_PROJD + NB_PROJP) {
        proj_direct<F_PROT>(xp, wpt, bp, xa, N_PROT, N_DRUG, bid - NB_PROJD);
    } else {
        int blk = bid - NB_PROJD - NB_PROJP;
        int t = threadIdx.x;
        lh[t] = 0;
        __syncthreads();
        int eb = blk * CH, ee = min(NE, eb + CH);
        for (int e = eb + t; e < ee; e += 256)
            atomicAdd(&lh[((unsigned)ei[NE + e]) >> 8], 1u);
        __syncthreads();
        bhist[(size_t)t * NBK1 + blk] = lh[t];
    }
}

// ---------------- scan step A: per-bucket row sums ----------------
__global__ __launch_bounds__(256) void kA(const unsigned* __restrict__ bhist,
                                          unsigned* __restrict__ rsum) {
    __shared__ unsigned s[256];
    int j = blockIdx.x, t = threadIdx.x;
    s[t] = bhist[(size_t)j * NBK1 + t];
    __syncthreads();
    for (int off = 128; off; off >>= 1) {
        if (t < off) s[t] += s[t + off];
        __syncthreads();
    }
    if (t == 0) rsum[j] = s[0];
}

// ---------------- merged scan: bucket bases + per-bucket row scan ----------------
__global__ __launch_bounds__(256) void kC2(unsigned* __restrict__ bhist,
                                           const unsigned* __restrict__ rsum,
                                           unsigned* __restrict__ rbase) {
    __shared__ unsigned sb[256], s[256];
    int j = blockIdx.x, t = threadIdx.x;
    unsigned rc = rsum[t];
    sb[t] = rc;
    __syncthreads();
    for (int off = 1; off < 256; off <<= 1) {
        unsigned v = sb[t]; unsigned u = (t >= off) ? sb[t - off] : 0;
        __syncthreads(); sb[t] = v + u; __syncthreads();
    }
    if (j == 0) {
        rbase[t] = sb[t] - rc;
        if (t == 255) rbase[256] = sb[255];     // == NE
    }
    unsigned rb = (j > 0) ? sb[j - 1] : 0;
    unsigned c = bhist[(size_t)j * NBK1 + t];
    s[t] = c;
    __syncthreads();
    for (int off = 1; off < 256; off <<= 1) {
        unsigned v = s[t]; unsigned u = (t >= off) ? s[t - off] : 0;
        __syncthreads(); s[t] = v + u; __syncthreads();
    }
    bhist[(size_t)j * NBK1 + t] = rb + s[t] - c;
}

// ---------------- bucket partition-scatter, XCD-contiguous chunk remap ----------------
__global__ __launch_bounds__(256) void k_part(
    const int* __restrict__ ei, const unsigned* __restrict__ base,
    unsigned* __restrict__ tmp) {
    __shared__ unsigned lcur[256];
    int bid = blockIdx.x;
    int c = ((bid & 7) << 5) | (bid >> 3);
    int t = threadIdx.x;
    lcur[t] = base[(size_t)t * NBK1 + c];
    __syncthreads();
    int eb = c * CH, ee = min(NE, eb + CH);
    for (int e = eb + t; e < ee; e += 256) {
        unsigned s = (unsigned)ei[e];
        unsigned d = (unsigned)ei[NE + e];
        unsigned pos = atomicAdd(&lcur[d >> 8], 1u);
        tmp[pos] = ((d & 255u) << 16) | s;
    }
}

// ---------------- fused: per-bucket CSR finalize || conv layer 0 ----------------
__global__ __launch_bounds__(256) void k_csrconv(
    const unsigned* __restrict__ tmp, const unsigned* __restrict__ rbase,
    int* __restrict__ rp, float* __restrict__ dis, unsigned short* __restrict__ csr,
    const _Float16* __restrict__ xa, const _Float16* __restrict__ cwt,
    _Float16* __restrict__ xw) {
    __shared__ unsigned lbin[256], lofs[256], lcur[256];
    int bid = blockIdx.x;
    if (bid >= NB_BKT) {
        conv_direct(xa, cwt, xw, bid - NB_BKT);
        return;
    }
    int b = bid, t = threadIdx.x;
    unsigned nb0 = rbase[b], nb1 = rbase[b + 1];
    lbin[t] = 0;
    __syncthreads();
    for (unsigned i = nb0 + t; i < nb1; i += 256)
        atomicAdd(&lbin[tmp[i] >> 16], 1u);
    __syncthreads();
    unsigned c = lbin[t];
    lofs[t] = c;
    __syncthreads();
    for (int off = 1; off < 256; off <<= 1) {
        unsigned v = lofs[t]; unsigned u = (t >= off) ? lofs[t - off] : 0;
        __syncthreads(); lofs[t] = v + u; __syncthreads();
    }
    unsigned r = nb0 + lofs[t] - c;
    int node = b * 256 + t;
    if (node < NN) {
        rp[node] = (int)r;
        dis[node] = rsqrtf((float)c + 1.0f);
    }
    lcur[t] = r;
    __syncthreads();
    for (unsigned i = nb0 + t; i < nb1; i += 256) {
        unsigned rec = tmp[i];
        unsigned pos = atomicAdd(&lcur[rec >> 16], 1u);
        csr[pos] = (unsigned short)(rec & 0xffffu);
    }
    if (b == 0 && t == 0) rp[NN] = NE;
}

// ---------------- standalone conv (layers 1,2) ----------------
__global__ __launch_bounds__(256) void k_conv(
    const _Float16* __restrict__ X, const _Float16* __restrict__ Wt,
    _Float16* __restrict__ out) {
    conv_direct(X, Wt, out, blockIdx.x);
}

// ---------------- SpMM oct-structure: 8 edge slots/wave, h8 (16B) per lane ----------------
template <bool FIRST, bool LAST>
__global__ __launch_bounds__(256) void k_spmm4(
    const int* __restrict__ rp, const unsigned short* __restrict__ csr,
    unsigned* __restrict__ pack, const float* __restrict__ dis,
    const _Float16* __restrict__ xin,
    const float* __restrict__ bias, _Float16* __restrict__ xout,
    const float* __restrict__ lw, const float* __restrict__ lb,
    float* __restrict__ y) {
    int lane = threadIdx.x & 63;
    int d = blockIdx.x * 4 + (threadIdx.x >> 6);   // NN % 4 == 0
    int o = lane >> 3, g = lane & 7;
    int beg = rp[d], end = rp[d + 1];
    float dd = dis[d];
    float acc[8];
    #pragma unroll
    for (int i = 0; i < 8; ++i) acc[i] = 0.f;

    int n = end - beg; if (n > 64) n = 64;
    unsigned rv = 0;
    if (lane < n) {
        if (FIRST) {
            int s = csr[beg + lane];
            float w0 = dis[s] * dd;
            rv = (unsigned)s | ((unsigned)__half_as_ushort(__float2half(w0)) << 16);
            pack[beg + lane] = rv;
        } else rv = pack[beg + lane];
    }
    for (int b0 = beg; b0 < end; ) {
        int nb = b0 + 64;
        int n2 = end - nb; if (n2 > 64) n2 = 64;
        unsigned rv2 = 0;
        if (n2 > 0 && lane < n2) {
            if (FIRST) {
                int s = csr[nb + lane];
                float w0 = dis[s] * dd;
                rv2 = (unsigned)s | ((unsigned)__half_as_ushort(__float2half(w0)) << 16);
                pack[nb + lane] = rv2;
            } else rv2 = pack[nb + lane];
        }
        int nsteps = (n + 7) >> 3;                 // <= 8
        #pragma unroll 4
        for (int jj = 0; jj < nsteps; ++jj) {
            unsigned r = __shfl(rv, jj * 8 + o);   // rv==0 masks idx>=n (w==0)
            float w = __half2float(__ushort_as_half((unsigned short)(r >> 16)));
            h8 xv = *(const h8*)&xin[((r & 0xffffu) << 6) + (g << 3)];
            #pragma unroll
            for (int i = 0; i < 8; ++i) acc[i] += w * (float)xv[i];
        }
        b0 = nb; n = n2; rv = rv2;
    }
    // reduce across the 8 octs -> full sums replicated
    #pragma unroll
    for (int off = 8; off < 64; off <<= 1)
        #pragma unroll
        for (int i = 0; i < 8; ++i) acc[i] += __shfl_xor(acc[i], off);
    // self term
    h8 xs = *(const h8*)&xin[((unsigned)d << 6) + (g << 3)];
    float sn = dd * dd;
    #pragma unroll
    for (int i = 0; i < 8; ++i) acc[i] += sn * (float)xs[i];

    if (LAST) {
        float4 l0 = *(const float4*)&lw[g << 3];
        float4 l1 = *(const float4*)&lw[(g << 3) + 4];
        float t = acc[0] * l0.x + acc[1] * l0.y + acc[2] * l0.z + acc[3] * l0.w
                + acc[4] * l1.x + acc[5] * l1.y + acc[6] * l1.z + acc[7] * l1.w;
        t += __shfl_xor(t, 1); t += __shfl_xor(t, 2); t += __shfl_xor(t, 4);
        if (lane == 0) y[d] = t + lb[0];
    } else if (o == 0) {
        float4 b0 = *(const float4*)&bias[g << 3];
        float4 b1 = *(const float4*)&bias[(g << 3) + 4];
        h8 hv;
        hv[0] = (_Float16)fmaxf(acc[0] + b0.x, 0.f);
        hv[1] = (_Float16)fmaxf(acc[1] + b0.y, 0.f);
        hv[2] = (_Float16)fmaxf(acc[2] + b0.z, 0.f);
        hv[3] = (_Float16)fmaxf(acc[3] + b0.w, 0.f);
        hv[4] = (_Float16)fmaxf(acc[4] + b1.x, 0.f);
        hv[5] = (_Float16)fmaxf(acc[5] + b1.y, 0.f);
        hv[6] = (_Float16)fmaxf(acc[6] + b1.z, 0.f);
        hv[7] = (_Float16)fmaxf(acc[7] + b1.w, 0.f);
        *(h8*)(xout + ((size_t)d << 6) + (g << 3)) = hv;
    }
}

// ---------------- edge scoring: sigmoid(y[src]*y[dst]) ----------------
__global__ void k_out(const float* __restrict__ y, const int* __restrict__ ls,
                      const int* __restrict__ ld, float* __restrict__ out) {
    int e = blockIdx.x * blockDim.x + threadIdx.x;
    if (e < NL) {
        float z = y[ls[e]] * y[ld[e]];
        out[e] = 1.f / (1.f + __expf(-z));
    }
}

static inline size_t up256(size_t x) { return (x + 255) & ~(size_t)255; }

extern "C" void kernel_launch(void* const* d_in, const int* in_sizes, int n_in,
                              void* d_out, int out_size, void* d_ws, size_t ws_size,
                              hipStream_t stream) {
    const float* x_drug = (const float*)d_in[0];
    const float* x_prot = (const float*)d_in[1];
    const float* W_drug = (const float*)d_in[2];
    const float* b_drug = (const float*)d_in[3];
    const float* W_prot = (const float*)d_in[4];
    const float* b_prot = (const float*)d_in[5];
    const float* conv_W = (const float*)d_in[6];
    const float* conv_b = (const float*)d_in[7];
    const float* lin_W  = (const float*)d_in[8];
    const float* lin_b  = (const float*)d_in[9];
    const int*   ei     = (const int*)d_in[10];
    const int*   lsrc   = (const int*)d_in[11];
    const int*   ldst   = (const int*)d_in[12];
    float* out = (float*)d_out;

    char* w = (char*)d_ws;
    size_t off = 0;
    unsigned* bhist = (unsigned*)(w + off); off = up256(off + (size_t)256 * NBK1 * 4);
    unsigned* rsum  = (unsigned*)(w + off); off = up256(off + 256 * 4);
    unsigned* rbase = (unsigned*)(w + off); off = up256(off + 257 * 4);
    unsigned* tmp   = (unsigned*)(w + off); off = up256(off + (size_t)NE * 4);
    unsigned short* csr = (unsigned short*)(w + off); off = up256(off + (size_t)NE * 2);
    unsigned* pack  = (unsigned*)(w + off); off = up256(off + (size_t)NE * 4);
    int*    rp   = (int*)(w + off);    off = up256(off + (size_t)(NN + 1) * 4);
    float*  dis  = (float*)(w + off);  off = up256(off + (size_t)NN * 4);
    _Float16* xa = (_Float16*)(w + off); off = up256(off + (size_t)NN * H * 2);
    _Float16* xb = (_Float16*)(w + off); off = up256(off + (size_t)NN * H * 2);
    _Float16* xw = (_Float16*)(w + off); off = up256(off + (size_t)NN * H * 2);
    float*  y    = (float*)(w + off);  off = up256(off + (size_t)NN * 4);
    _Float16* wdt = (_Float16*)(w + off); off = up256(off + (size_t)64 * F_DRUG * 2);
    _Float16* wpt = (_Float16*)(w + off); off = up256(off + (size_t)64 * F_PROT * 2);
    _Float16* cwt = (_Float16*)(w + off); off = up256(off + (size_t)3 * 64 * 64 * 2);

    k_wprep<<<64, 256, 0, stream>>>(W_drug, W_prot, conv_W, wdt, wpt, cwt);

    // proj_drug || proj_prot || coarse hist
    k_front<<<NB_PROJD + NB_PROJP + NBK1, 256, 0, stream>>>(
        x_drug, wdt, b_drug, x_prot, wpt, b_prot, ei, bhist, xa);

    kA<<<256, 256, 0, stream>>>(bhist, rsum);
    kC2<<<256, 256, 0, stream>>>(bhist, rsum, rbase);

    // bucket partition-scatter (XCD-contiguous chunks)
    k_part<<<NBK1, 256, 0, stream>>>(ei, bhist, tmp);

    // per-bucket CSR finalize || conv layer 0 (xa -> xw)
    k_csrconv<<<NB_BKT + NB_CONV, 256, 0, stream>>>(
        tmp, rbase, rp, dis, csr, xa, cwt, xw);

    // layer 0: spmm(xw) -> xb (builds pack)
    k_spmm4<true, false><<<NB_ROW4, 256, 0, stream>>>(
        rp, csr, pack, dis, xw, conv_b, xb, nullptr, nullptr, nullptr);
    // layer 1
    k_conv<<<NB_CONV, 256, 0, stream>>>(xb, cwt + 4096, xw);
    k_spmm4<false, false><<<NB_ROW4, 256, 0, stream>>>(
        rp, csr, pack, dis, xw, conv_b + 64, xa, nullptr, nullptr, nullptr);
    // layer 2 (fused lin head)
    k_conv<<<NB_CONV, 256, 0, stream>>>(xa, cwt + 8192, xw);
    k_spmm4<false, true><<<NB_ROW4, 256, 0, stream>>>(
        rp, csr, pack, dis, xw, conv_b + 128, nullptr, lin_W, lin_b, y);

    k_out<<<(NL + 255) / 256, 256, 0, stream>>>(y, lsrc, ldst, out);
}

// Round 15
// 174.142 us; speedup vs baseline: 1.5280x; 1.0451x over previous
//
#include <hip/hip_runtime.h>
#include <hip/hip_fp16.h>
#include <math.h>

#define N_DRUG 20000
#define N_PROT 30000
#define NN (N_DRUG + N_PROT)
#define F_DRUG 128
#define F_PROT 256
#define H 64
#define NE 1600000
#define NL 200000

#define NB_PROJD ((N_DRUG + 255) / 256)          // 79  (256 rows/block)
#define NB_PROJP ((N_PROT + 255) / 256)          // 118
#define NB_CONV  ((NN + 255) / 256)              // 196 (256 rows/block)
#define NB_ROW16 (NN / 16)                       // 3125 (16 rows/block; NN%16==0)
#define NBK1 256                                  // partition chunks
#define CH   ((NE + NBK1 - 1) / NBK1)            // 6250 edges/chunk
#define NB_BKT ((NN + 255) / 256)                // 196 buckets

typedef _Float16 h8 __attribute__((ext_vector_type(8)));
typedef _Float16 h4 __attribute__((ext_vector_type(4)));
typedef float f32x4 __attribute__((ext_vector_type(4)));

#define MFMA16(a, b, c) __builtin_amdgcn_mfma_f32_16x16x32_f16((a), (b), (c), 0, 0, 0)

// ---------------- weight prep: transpose + fp16 ([c][k] layout) ----------------
__global__ __launch_bounds__(256) void k_wprep(
    const float* __restrict__ Wd, const float* __restrict__ Wp,
    const float* __restrict__ cw,
    _Float16* __restrict__ wdt, _Float16* __restrict__ wpt,
    _Float16* __restrict__ cwt) {
    int i = blockIdx.x * 256 + threadIdx.x;
    if (i < 64 * F_DRUG) {
        int c = i / F_DRUG, k = i % F_DRUG;
        wdt[i] = (_Float16)Wd[k * H + c];
    }
    if (i < 64 * F_PROT) {
        int c = i / F_PROT, k = i % F_PROT;
        wpt[i] = (_Float16)Wp[k * H + c];
    }
    if (i < 3 * 64 * 64) {
        int l = i >> 12, r = i & 4095;
        int c = r >> 6, k = r & 63;
        cwt[i] = (_Float16)cw[(l << 12) + k * H + c];
    }
}

// ---------------- zero-LDS MFMA projection: out = relu(X@W + b), 64 rows/wave ----------------
template <int F>
__device__ __forceinline__ void proj_direct(
    const float* __restrict__ X, const _Float16* __restrict__ Wt,
    const float* __restrict__ bias, _Float16* __restrict__ out,
    int rows, int row_off, int bid) {
    int l = threadIdx.x & 63, wvi = threadIdx.x >> 6;
    int lr = l & 15, lq = l >> 4;
    int r0 = bid * 256 + wvi * 64;
    f32x4 acc[4][4];
    #pragma unroll
    for (int rt = 0; rt < 4; ++rt)
        #pragma unroll
        for (int n = 0; n < 4; ++n) acc[rt][n] = (f32x4){0.f, 0.f, 0.f, 0.f};

    for (int k0 = 0; k0 < F; k0 += 64) {
        h8 af[4][2];
        #pragma unroll
        for (int n = 0; n < 4; ++n)
            #pragma unroll
            for (int kk = 0; kk < 2; ++kk)
                af[n][kk] = *(const h8*)&Wt[(size_t)(n * 16 + lr) * F + k0 + kk * 32 + lq * 8];
        #pragma unroll
        for (int rt = 0; rt < 4; ++rt) {
            int r = r0 + rt * 16 + lr;
            int rc = (r < rows) ? r : (rows - 1);
            h8 bf[2];
            #pragma unroll
            for (int kk = 0; kk < 2; ++kk) {
                const float* xp = X + (size_t)rc * F + k0 + kk * 32 + lq * 8;
                float4 a = *(const float4*)xp;
                float4 b = *(const float4*)(xp + 4);
                h8 t;
                t[0] = (_Float16)a.x; t[1] = (_Float16)a.y;
                t[2] = (_Float16)a.z; t[3] = (_Float16)a.w;
                t[4] = (_Float16)b.x; t[5] = (_Float16)b.y;
                t[6] = (_Float16)b.z; t[7] = (_Float16)b.w;
                bf[kk] = t;
            }
            #pragma unroll
            for (int n = 0; n < 4; ++n) {
                acc[rt][n] = MFMA16(af[n][0], bf[0], acc[rt][n]);
                acc[rt][n] = MFMA16(af[n][1], bf[1], acc[rt][n]);
            }
        }
    }
    #pragma unroll
    for (int rt = 0; rt < 4; ++rt) {
        int r = r0 + rt * 16 + lr;
        if (r < rows) {
            #pragma unroll
            for (int n = 0; n < 4; ++n) {
                int c = n * 16 + lq * 4;
                float4 bv = *(const float4*)&bias[c];
                h4 hv;
                hv[0] = (_Float16)fmaxf(acc[rt][n][0] + bv.x, 0.f);
                hv[1] = (_Float16)fmaxf(acc[rt][n][1] + bv.y, 0.f);
                hv[2] = (_Float16)fmaxf(acc[rt][n][2] + bv.z, 0.f);
                hv[3] = (_Float16)fmaxf(acc[rt][n][3] + bv.w, 0.f);
                *(h4*)(out + (size_t)(row_off + r) * H + c) = hv;
            }
        }
    }
}

// ---------------- zero-LDS MFMA conv: xw = x @ Wl (fp16 in/out, fp32 acc) ----------------
__device__ __forceinline__ void conv_direct(
    const _Float16* __restrict__ xh, const _Float16* __restrict__ Wt,
    _Float16* __restrict__ xout, int bid) {
    int l = threadIdx.x & 63, wvi = threadIdx.x >> 6;
    int lr = l & 15, lq = l >> 4;
    h8 af[4][2];
    #pragma unroll
    for (int n = 0; n < 4; ++n)
        #pragma unroll
        for (int kk = 0; kk < 2; ++kk)
            af[n][kk] = *(const h8*)&Wt[(size_t)(n * 16 + lr) * 64 + kk * 32 + lq * 8];
    int r0 = bid * 256 + wvi * 64;
    #pragma unroll
    for (int rt = 0; rt < 4; ++rt) {
        int r = r0 + rt * 16 + lr;
        int rc = (r < NN) ? r : (NN - 1);
        h8 bf0 = *(const h8*)&xh[(size_t)rc * H + lq * 8];
        h8 bf1 = *(const h8*)&xh[(size_t)rc * H + 32 + lq * 8];
        f32x4 a[4];
        #pragma unroll
        for (int n = 0; n < 4; ++n) {
            a[n] = (f32x4){0.f, 0.f, 0.f, 0.f};
            a[n] = MFMA16(af[n][0], bf0, a[n]);
            a[n] = MFMA16(af[n][1], bf1, a[n]);
        }
        if (r < NN) {
            #pragma unroll
            for (int n = 0; n < 4; ++n) {
                int c = n * 16 + lq * 4;
                h4 hv;
                hv[0] = (_Float16)a[n][0]; hv[1] = (_Float16)a[n][1];
                hv[2] = (_Float16)a[n][2]; hv[3] = (_Float16)a[n][3];
                *(h4*)(xout + (size_t)r * H + c) = hv;
            }
        }
    }
}

// ---------------- fused front: proj_drug || proj_prot || coarse bucket hist ----------------
__global__ __launch_bounds__(256) void k_front(
    const float* __restrict__ xd, const _Float16* __restrict__ wdt, const float* __restrict__ bd,
    const float* __restrict__ xp, const _Float16* __restrict__ wpt, const float* __restrict__ bp,
    const int* __restrict__ ei, unsigned* __restrict__ bhist, _Float16* __restrict__ xa) {
    __shared__ unsigned lh[256];
    int bid = blockIdx.x;
    if (bid < NB_PROJD) {
        proj_direct<F_DRUG>(xd, wdt, bd, xa, N_DRUG, 0, bid);
    } else if (bid < NB_PROJD + NB_PROJP) {
        proj_direct<F_PROT>(xp, wpt, bp, xa, N_PROT, N_DRUG, bid - NB_PROJD);
    } else {
        int blk = bid - NB_PROJD - NB_PROJP;
        int t = threadIdx.x;
        lh[t] = 0;
        __syncthreads();
        int eb = blk * CH, ee = min(NE, eb + CH);
        for (int e = eb + t; e < ee; e += 256)
            atomicAdd(&lh[((unsigned)ei[NE + e]) >> 8], 1u);
        __syncthreads();
        bhist[(size_t)t * NBK1 + blk] = lh[t];
    }
}

// ---------------- scan step A: per-bucket row sums ----------------
__global__ __launch_bounds__(256) void kA(const unsigned* __restrict__ bhist,
                                          unsigned* __restrict__ rsum) {
    __shared__ unsigned s[256];
    int j = blockIdx.x, t = threadIdx.x;
    s[t] = bhist[(size_t)j * NBK1 + t];
    __syncthreads();
    for (int off = 128; off; off >>= 1) {
        if (t < off) s[t] += s[t + off];
        __syncthreads();
    }
    if (t == 0) rsum[j] = s[0];
}

// ---------------- merged scan: bucket bases + per-bucket row scan ----------------
__global__ __launch_bounds__(256) void kC2(unsigned* __restrict__ bhist,
                                           const unsigned* __restrict__ rsum,
                                           unsigned* __restrict__ rbase) {
    __shared__ unsigned sb[256], s[256];
    int j = blockIdx.x, t = threadIdx.x;
    unsigned rc = rsum[t];
    sb[t] = rc;
    __syncthreads();
    for (int off = 1; off < 256; off <<= 1) {
        unsigned v = sb[t]; unsigned u = (t >= off) ? sb[t - off] : 0;
        __syncthreads(); sb[t] = v + u; __syncthreads();
    }
    if (j == 0) {
        rbase[t] = sb[t] - rc;
        if (t == 255) rbase[256] = sb[255];     // == NE
    }
    unsigned rb = (j > 0) ? sb[j - 1] : 0;
    unsigned c = bhist[(size_t)j * NBK1 + t];
    s[t] = c;
    __syncthreads();
    for (int off = 1; off < 256; off <<= 1) {
        unsigned v = s[t]; unsigned u = (t >= off) ? s[t - off] : 0;
        __syncthreads(); s[t] = v + u; __syncthreads();
    }
    bhist[(size_t)j * NBK1 + t] = rb + s[t] - c;
}

// ---------------- bucket partition-scatter, XCD-contiguous chunk remap ----------------
__global__ __launch_bounds__(256) void k_part(
    const int* __restrict__ ei, const unsigned* __restrict__ base,
    unsigned* __restrict__ tmp) {
    __shared__ unsigned lcur[256];
    int bid = blockIdx.x;
    int c = ((bid & 7) << 5) | (bid >> 3);
    int t = threadIdx.x;
    lcur[t] = base[(size_t)t * NBK1 + c];
    __syncthreads();
    int eb = c * CH, ee = min(NE, eb + CH);
    for (int e = eb + t; e < ee; e += 256) {
        unsigned s = (unsigned)ei[e];
        unsigned d = (unsigned)ei[NE + e];
        unsigned pos = atomicAdd(&lcur[d >> 8], 1u);
        tmp[pos] = ((d & 255u) << 16) | s;
    }
}

// ---------------- fused: per-bucket CSR finalize || conv layer 0 ----------------
__global__ __launch_bounds__(256) void k_csrconv(
    const unsigned* __restrict__ tmp, const unsigned* __restrict__ rbase,
    int* __restrict__ rp, float* __restrict__ dis, unsigned short* __restrict__ csr,
    const _Float16* __restrict__ xa, const _Float16* __restrict__ cwt,
    _Float16* __restrict__ xw) {
    __shared__ unsigned lbin[256], lofs[256], lcur[256];
    int bid = blockIdx.x;
    if (bid >= NB_BKT) {
        conv_direct(xa, cwt, xw, bid - NB_BKT);
        return;
    }
    int b = bid, t = threadIdx.x;
    unsigned nb0 = rbase[b], nb1 = rbase[b + 1];
    lbin[t] = 0;
    __syncthreads();
    for (unsigned i = nb0 + t; i < nb1; i += 256)
        atomicAdd(&lbin[tmp[i] >> 16], 1u);
    __syncthreads();
    unsigned c = lbin[t];
    lofs[t] = c;
    __syncthreads();
    for (int off = 1; off < 256; off <<= 1) {
        unsigned v = lofs[t]; unsigned u = (t >= off) ? lofs[t - off] : 0;
        __syncthreads(); lofs[t] = v + u; __syncthreads();
    }
    unsigned r = nb0 + lofs[t] - c;
    int node = b * 256 + t;
    if (node < NN) {
        rp[node] = (int)r;
        dis[node] = rsqrtf((float)c + 1.0f);
    }
    lcur[t] = r;
    __syncthreads();
    for (unsigned i = nb0 + t; i < nb1; i += 256) {
        unsigned rec = tmp[i];
        unsigned pos = atomicAdd(&lcur[rec >> 16], 1u);
        csr[pos] = (unsigned short)(rec & 0xffffu);
    }
    if (b == 0 && t == 0) rp[NN] = NE;
}

// ---------------- SpMM oct-structure + fused next-layer conv via MFMA epilogue ----------------
// Block = 16 dst rows; each wave walks 4 rows sequentially (edge-loop body identical
// to the proven round-13 structure). Non-LAST: relu'd aggregate rows staged in a
// 2KB XOR-swizzled LDS tile, one barrier, 2 MFMAs/wave compute v @ W_next -> xw out.
// LAST: per-row lin-head dot -> y (no LDS/MFMA).
template <bool FIRST, bool LAST>
__global__ __launch_bounds__(256) void k_spmm5(
    const int* __restrict__ rp, const unsigned short* __restrict__ csr,
    unsigned* __restrict__ pack, const float* __restrict__ dis,
    const _Float16* __restrict__ xin, const _Float16* __restrict__ Wt,
    const float* __restrict__ bias, _Float16* __restrict__ xwout,
    const float* __restrict__ lw, const float* __restrict__ lb,
    float* __restrict__ y) {
    __shared__ _Float16 v[16 * 64];
    int lane = threadIdx.x & 63, wvi = threadIdx.x >> 6;
    int o = lane >> 3, g = lane & 7;
    int d0 = blockIdx.x * 16;

    #pragma unroll
    for (int rr = 0; rr < 4; ++rr) {
        int d = d0 + wvi * 4 + rr;
        int beg = rp[d], end = rp[d + 1];
        float dd = dis[d];
        float acc[8];
        #pragma unroll
        for (int i = 0; i < 8; ++i) acc[i] = 0.f;

        int n = end - beg; if (n > 64) n = 64;
        unsigned rv = 0;
        if (lane < n) {
            if (FIRST) {
                int s = csr[beg + lane];
                float w0 = dis[s] * dd;
                rv = (unsigned)s | ((unsigned)__half_as_ushort(__float2half(w0)) << 16);
                pack[beg + lane] = rv;
            } else rv = pack[beg + lane];
        }
        for (int b0 = beg; b0 < end; ) {
            int nb = b0 + 64;
            int n2 = end - nb; if (n2 > 64) n2 = 64;
            unsigned rv2 = 0;
            if (n2 > 0 && lane < n2) {
                if (FIRST) {
                    int s = csr[nb + lane];
                    float w0 = dis[s] * dd;
                    rv2 = (unsigned)s | ((unsigned)__half_as_ushort(__float2half(w0)) << 16);
                    pack[nb + lane] = rv2;
                } else rv2 = pack[nb + lane];
            }
            int nsteps = (n + 7) >> 3;                 // <= 8
            #pragma unroll 4
            for (int jj = 0; jj < nsteps; ++jj) {
                unsigned r = __shfl(rv, jj * 8 + o);   // rv==0 masks idx>=n (w==0)
                float w = __half2float(__ushort_as_half((unsigned short)(r >> 16)));
                h8 xv = *(const h8*)&xin[((r & 0xffffu) << 6) + (g << 3)];
                #pragma unroll
                for (int i = 0; i < 8; ++i) acc[i] += w * (float)xv[i];
            }
            b0 = nb; n = n2; rv = rv2;
        }
        // reduce across the 8 octs -> full sums replicated
        #pragma unroll
        for (int off = 8; off < 64; off <<= 1)
            #pragma unroll
            for (int i = 0; i < 8; ++i) acc[i] += __shfl_xor(acc[i], off);
        // self term
        h8 xs = *(const h8*)&xin[((unsigned)d << 6) + (g << 3)];
        float sn = dd * dd;
        #pragma unroll
        for (int i = 0; i < 8; ++i) acc[i] += sn * (float)xs[i];

        if (LAST) {
            float4 b0v = *(const float4*)&bias[g << 3];
            float4 b1v = *(const float4*)&bias[(g << 3) + 4];
            float vv[8];
            vv[0] = fmaxf(acc[0] + b0v.x, 0.f); vv[1] = fmaxf(acc[1] + b0v.y, 0.f);
            vv[2] = fmaxf(acc[2] + b0v.z, 0.f); vv[3] = fmaxf(acc[3] + b0v.w, 0.f);
            vv[4] = fmaxf(acc[4] + b1v.x, 0.f); vv[5] = fmaxf(acc[5] + b1v.y, 0.f);
            vv[6] = fmaxf(acc[6] + b1v.z, 0.f); vv[7] = fmaxf(acc[7] + b1v.w, 0.f);
            float4 l0 = *(const float4*)&lw[g << 3];
            float4 l1 = *(const float4*)&lw[(g << 3) + 4];
            float t = vv[0] * l0.x + vv[1] * l0.y + vv[2] * l0.z + vv[3] * l0.w
                    + vv[4] * l1.x + vv[5] * l1.y + vv[6] * l1.z + vv[7] * l1.w;
            t += __shfl_xor(t, 1); t += __shfl_xor(t, 2); t += __shfl_xor(t, 4);
            if (lane == 0) y[d] = t + lb[0];
        } else if (o == 0) {
            float4 b0v = *(const float4*)&bias[g << 3];
            float4 b1v = *(const float4*)&bias[(g << 3) + 4];
            h8 hv;
            hv[0] = (_Float16)fmaxf(acc[0] + b0v.x, 0.f);
            hv[1] = (_Float16)fmaxf(acc[1] + b0v.y, 0.f);
            hv[2] = (_Float16)fmaxf(acc[2] + b0v.z, 0.f);
            hv[3] = (_Float16)fmaxf(acc[3] + b0v.w, 0.f);
            hv[4] = (_Float16)fmaxf(acc[4] + b1v.x, 0.f);
            hv[5] = (_Float16)fmaxf(acc[5] + b1v.y, 0.f);
            hv[6] = (_Float16)fmaxf(acc[6] + b1v.z, 0.f);
            hv[7] = (_Float16)fmaxf(acc[7] + b1v.w, 0.f);
            int rl = wvi * 4 + rr;
            // XOR-swizzle the 16B chunk index with row&7 (kills 128B-stride bank conflict)
            *(h8*)&v[rl * 64 + ((g ^ (rl & 7)) << 3)] = hv;
        }
    }

    if (!LAST) {
        __syncthreads();
        // MFMA epilogue: wave wvi computes cols wvi*16..+16 of (v @ W_next) for rows d0..d0+15.
        // Frag layout mirrors conv_direct (verified): A = Wt rows (cols of W), B = v rows.
        int lr = lane & 15, lq = lane >> 4;
        h8 af0 = *(const h8*)&Wt[(size_t)(wvi * 16 + lr) * 64 + lq * 8];
        h8 af1 = *(const h8*)&Wt[(size_t)(wvi * 16 + lr) * 64 + 32 + lq * 8];
        h8 bf0 = *(const h8*)&v[lr * 64 + ((lq ^ (lr & 7)) << 3)];
        h8 bf1 = *(const h8*)&v[lr * 64 + (((4 + lq) ^ (lr & 7)) << 3)];
        f32x4 a = (f32x4){0.f, 0.f, 0.f, 0.f};
        a = MFMA16(af0, bf0, a);
        a = MFMA16(af1, bf1, a);
        // store: row (B-dim) = d0 + lr, col = wvi*16 + lq*4 + i  (same mapping as conv_direct)
        int c = wvi * 16 + lq * 4;
        h4 hv;
        hv[0] = (_Float16)a[0]; hv[1] = (_Float16)a[1];
        hv[2] = (_Float16)a[2]; hv[3] = (_Float16)a[3];
        *(h4*)(xwout + (size_t)(d0 + lr) * H + c) = hv;
    }
}

// ---------------- edge scoring: sigmoid(y[src]*y[dst]) ----------------
__global__ void k_out(const float* __restrict__ y, const int* __restrict__ ls,
                      const int* __restrict__ ld, float* __restrict__ out) {
    int e = blockIdx.x * blockDim.x + threadIdx.x;
    if (e < NL) {
        float z = y[ls[e]] * y[ld[e]];
        out[e] = 1.f / (1.f + __expf(-z));
    }
}

static inline size_t up256(size_t x) { return (x + 255) & ~(size_t)255; }

extern "C" void kernel_launch(void* const* d_in, const int* in_sizes, int n_in,
                              void* d_out, int out_size, void* d_ws, size_t ws_size,
                              hipStream_t stream) {
    const float* x_drug = (const float*)d_in[0];
    const float* x_prot = (const float*)d_in[1];
    const float* W_drug = (const float*)d_in[2];
    const float* b_drug = (const float*)d_in[3];
    const float* W_prot = (const float*)d_in[4];
    const float* b_prot = (const float*)d_in[5];
    const float* conv_W = (const float*)d_in[6];
    const float* conv_b = (const float*)d_in[7];
    const float* lin_W  = (const float*)d_in[8];
    const float* lin_b  = (const float*)d_in[9];
    const int*   ei     = (const int*)d_in[10];
    const int*   lsrc   = (const int*)d_in[11];
    const int*   ldst   = (const int*)d_in[12];
    float* out = (float*)d_out;

    char* w = (char*)d_ws;
    size_t off = 0;
    unsigned* bhist = (unsigned*)(w + off); off = up256(off + (size_t)256 * NBK1 * 4);
    unsigned* rsum  = (unsigned*)(w + off); off = up256(off + 256 * 4);
    unsigned* rbase = (unsigned*)(w + off); off = up256(off + 257 * 4);
    unsigned* tmp   = (unsigned*)(w + off); off = up256(off + (size_t)NE * 4);
    unsigned short* csr = (unsigned short*)(w + off); off = up256(off + (size_t)NE * 2);
    unsigned* pack  = (unsigned*)(w + off); off = up256(off + (size_t)NE * 4);
    int*    rp   = (int*)(w + off);    off = up256(off + (size_t)(NN + 1) * 4);
    float*  dis  = (float*)(w + off);  off = up256(off + (size_t)NN * 4);
    _Float16* xa = (_Float16*)(w + off); off = up256(off + (size_t)NN * H * 2);
    _Float16* xb = (_Float16*)(w + off); off = up256(off + (size_t)NN * H * 2);
    _Float16* xw = (_Float16*)(w + off); off = up256(off + (size_t)NN * H * 2);
    float*  y    = (float*)(w + off);  off = up256(off + (size_t)NN * 4);
    _Float16* wdt = (_Float16*)(w + off); off = up256(off + (size_t)64 * F_DRUG * 2);
    _Float16* wpt = (_Float16*)(w + off); off = up256(off + (size_t)64 * F_PROT * 2);
    _Float16* cwt = (_Float16*)(w + off); off = up256(off + (size_t)3 * 64 * 64 * 2);

    k_wprep<<<64, 256, 0, stream>>>(W_drug, W_prot, conv_W, wdt, wpt, cwt);

    // proj_drug || proj_prot || coarse hist
    k_front<<<NB_PROJD + NB_PROJP + NBK1, 256, 0, stream>>>(
        x_drug, wdt, b_drug, x_prot, wpt, b_prot, ei, bhist, xa);

    kA<<<256, 256, 0, stream>>>(bhist, rsum);
    kC2<<<256, 256, 0, stream>>>(bhist, rsum, rbase);

    // bucket partition-scatter (XCD-contiguous chunks)
    k_part<<<NBK1, 256, 0, stream>>>(ei, bhist, tmp);

    // per-bucket CSR finalize || conv layer 0 (xa -> xw0)
    k_csrconv<<<NB_BKT + NB_CONV, 256, 0, stream>>>(
        tmp, rbase, rp, dis, csr, xa, cwt, xw);

    // layer 0: spmm(xw0) -> xw1 (builds pack; conv1 fused via MFMA epilogue)
    k_spmm5<true, false><<<NB_ROW16, 256, 0, stream>>>(
        rp, csr, pack, dis, xw, cwt + 4096, conv_b, xb, nullptr, nullptr, nullptr);
    // layer 1: spmm(xw1) -> xw2 (conv2 fused)
    k_spmm5<false, false><<<NB_ROW16, 256, 0, stream>>>(
        rp, csr, pack, dis, xb, cwt + 8192, conv_b + 64, xa, nullptr, nullptr, nullptr);
    // layer 2: spmm(xw2) -> y (fused lin head)
    k_spmm5<false, true><<<NB_ROW16, 256, 0, stream>>>(
        rp, csr, pack, dis, xa, nullptr, conv_b + 128, nullptr, lin_W, lin_b, y);

    k_out<<<(NL + 255) / 256, 256, 0, stream>>>(y, lsrc, ldst, out);
}

// Round 16
// 168.459 us; speedup vs baseline: 1.5796x; 1.0337x over previous
//
#include <hip/hip_runtime.h>
#include <hip/hip_fp16.h>
#include <math.h>

#define N_DRUG 20000
#define N_PROT 30000
#define NN (N_DRUG + N_PROT)
#define F_DRUG 128
#define F_PROT 256
#define H 64
#define NE 1600000
#define NL 200000

#define NB_PROJD ((N_DRUG + 127) / 128)          // 157 (128 rows/block)
#define NB_PROJP ((N_PROT + 127) / 128)          // 235
#define NB_CONV  ((NN + 255) / 256)              // 196 (256 rows/block)
#define NB_ROW16 (NN / 16)                       // 3125 (16 rows/block; NN%16==0)
#define NBK1 256                                  // partition chunks
#define CH   6252                                 // edges/chunk (mult of 4; 256*6252 >= NE)
#define NB_BKT ((NN + 255) / 256)                // 196 buckets

typedef _Float16 h8 __attribute__((ext_vector_type(8)));
typedef _Float16 h4 __attribute__((ext_vector_type(4)));
typedef float f32x4 __attribute__((ext_vector_type(4)));

#define MFMA16(a, b, c) __builtin_amdgcn_mfma_f32_16x16x32_f16((a), (b), (c), 0, 0, 0)

// ---------------- weight prep: transpose + fp16 ([c][k] layout) ----------------
__global__ __launch_bounds__(256) void k_wprep(
    const float* __restrict__ Wd, const float* __restrict__ Wp,
    const float* __restrict__ cw,
    _Float16* __restrict__ wdt, _Float16* __restrict__ wpt,
    _Float16* __restrict__ cwt) {
    int i = blockIdx.x * 256 + threadIdx.x;
    if (i < 64 * F_DRUG) {
        int c = i / F_DRUG, k = i % F_DRUG;
        wdt[i] = (_Float16)Wd[k * H + c];
    }
    if (i < 64 * F_PROT) {
        int c = i / F_PROT, k = i % F_PROT;
        wpt[i] = (_Float16)Wp[k * H + c];
    }
    if (i < 3 * 64 * 64) {
        int l = i >> 12, r = i & 4095;
        int c = r >> 6, k = r & 63;
        cwt[i] = (_Float16)cw[(l << 12) + k * H + c];
    }
}

// ---------------- zero-LDS MFMA projection: out = relu(X@W + b), 32 rows/wave ----------------
template <int F>
__device__ __forceinline__ void proj_direct(
    const float* __restrict__ X, const _Float16* __restrict__ Wt,
    const float* __restrict__ bias, _Float16* __restrict__ out,
    int rows, int row_off, int bid) {
    int l = threadIdx.x & 63, wvi = threadIdx.x >> 6;
    int lr = l & 15, lq = l >> 4;
    int r0 = bid * 128 + wvi * 32;
    f32x4 acc[2][4];
    #pragma unroll
    for (int rt = 0; rt < 2; ++rt)
        #pragma unroll
        for (int n = 0; n < 4; ++n) acc[rt][n] = (f32x4){0.f, 0.f, 0.f, 0.f};

    for (int k0 = 0; k0 < F; k0 += 64) {
        h8 af[4][2];
        #pragma unroll
        for (int n = 0; n < 4; ++n)
            #pragma unroll
            for (int kk = 0; kk < 2; ++kk)
                af[n][kk] = *(const h8*)&Wt[(size_t)(n * 16 + lr) * F + k0 + kk * 32 + lq * 8];
        #pragma unroll
        for (int rt = 0; rt < 2; ++rt) {
            int r = r0 + rt * 16 + lr;
            int rc = (r < rows) ? r : (rows - 1);
            h8 bf[2];
            #pragma unroll
            for (int kk = 0; kk < 2; ++kk) {
                const float* xp = X + (size_t)rc * F + k0 + kk * 32 + lq * 8;
                float4 a = *(const float4*)xp;
                float4 b = *(const float4*)(xp + 4);
                h8 t;
                t[0] = (_Float16)a.x; t[1] = (_Float16)a.y;
                t[2] = (_Float16)a.z; t[3] = (_Float16)a.w;
                t[4] = (_Float16)b.x; t[5] = (_Float16)b.y;
                t[6] = (_Float16)b.z; t[7] = (_Float16)b.w;
                bf[kk] = t;
            }
            #pragma unroll
            for (int n = 0; n < 4; ++n) {
                acc[rt][n] = MFMA16(af[n][0], bf[0], acc[rt][n]);
                acc[rt][n] = MFMA16(af[n][1], bf[1], acc[rt][n]);
            }
        }
    }
    #pragma unroll
    for (int rt = 0; rt < 2; ++rt) {
        int r = r0 + rt * 16 + lr;
        if (r < rows) {
            #pragma unroll
            for (int n = 0; n < 4; ++n) {
                int c = n * 16 + lq * 4;
                float4 bv = *(const float4*)&bias[c];
                h4 hv;
                hv[0] = (_Float16)fmaxf(acc[rt][n][0] + bv.x, 0.f);
                hv[1] = (_Float16)fmaxf(acc[rt][n][1] + bv.y, 0.f);
                hv[2] = (_Float16)fmaxf(acc[rt][n][2] + bv.z, 0.f);
                hv[3] = (_Float16)fmaxf(acc[rt][n][3] + bv.w, 0.f);
                *(h4*)(out + (size_t)(row_off + r) * H + c) = hv;
            }
        }
    }
}

// ---------------- zero-LDS MFMA conv: xw = x @ Wl (fp16 in/out, fp32 acc) ----------------
__device__ __forceinline__ void conv_direct(
    const _Float16* __restrict__ xh, const _Float16* __restrict__ Wt,
    _Float16* __restrict__ xout, int bid) {
    int l = threadIdx.x & 63, wvi = threadIdx.x >> 6;
    int lr = l & 15, lq = l >> 4;
    h8 af[4][2];
    #pragma unroll
    for (int n = 0; n < 4; ++n)
        #pragma unroll
        for (int kk = 0; kk < 2; ++kk)
            af[n][kk] = *(const h8*)&Wt[(size_t)(n * 16 + lr) * 64 + kk * 32 + lq * 8];
    int r0 = bid * 256 + wvi * 64;
    #pragma unroll
    for (int rt = 0; rt < 4; ++rt) {
        int r = r0 + rt * 16 + lr;
        int rc = (r < NN) ? r : (NN - 1);
        h8 bf0 = *(const h8*)&xh[(size_t)rc * H + lq * 8];
        h8 bf1 = *(const h8*)&xh[(size_t)rc * H + 32 + lq * 8];
        f32x4 a[4];
        #pragma unroll
        for (int n = 0; n < 4; ++n) {
            a[n] = (f32x4){0.f, 0.f, 0.f, 0.f};
            a[n] = MFMA16(af[n][0], bf0, a[n]);
            a[n] = MFMA16(af[n][1], bf1, a[n]);
        }
        if (r < NN) {
            #pragma unroll
            for (int n = 0; n < 4; ++n) {
                int c = n * 16 + lq * 4;
                h4 hv;
                hv[0] = (_Float16)a[n][0]; hv[1] = (_Float16)a[n][1];
                hv[2] = (_Float16)a[n][2]; hv[3] = (_Float16)a[n][3];
                *(h4*)(xout + (size_t)r * H + c) = hv;
            }
        }
    }
}

// ---------------- fused front: proj_drug || proj_prot || coarse bucket hist (int4) ----------------
__global__ __launch_bounds__(256) void k_front(
    const float* __restrict__ xd, const _Float16* __restrict__ wdt, const float* __restrict__ bd,
    const float* __restrict__ xp, const _Float16* __restrict__ wpt, const float* __restrict__ bp,
    const int* __restrict__ ei, unsigned* __restrict__ bhist, _Float16* __restrict__ xa) {
    __shared__ unsigned lh[256];
    int bid = blockIdx.x;
    if (bid < NB_PROJD) {
        proj_direct<F_DRUG>(xd, wdt, bd, xa, N_DRUG, 0, bid);
    } else if (bid < NB_PROJD + NB_PROJP) {
        proj_direct<F_PROT>(xp, wpt, bp, xa, N_PROT, N_DRUG, bid - NB_PROJD);
    } else {
        int blk = bid - NB_PROJD - NB_PROJP;
        int t = threadIdx.x;
        lh[t] = 0;
        __syncthreads();
        int eb = blk * CH, ee = min(NE, eb + CH);
        for (int e = eb + t * 4; e < ee; e += 1024) {
            int4 d4 = *(const int4*)&ei[NE + e];
            atomicAdd(&lh[((unsigned)d4.x) >> 8], 1u);
            atomicAdd(&lh[((unsigned)d4.y) >> 8], 1u);
            atomicAdd(&lh[((unsigned)d4.z) >> 8], 1u);
            atomicAdd(&lh[((unsigned)d4.w) >> 8], 1u);
        }
        __syncthreads();
        bhist[(size_t)t * NBK1 + blk] = lh[t];
    }
}

// ---------------- scan step A: per-bucket row sums ----------------
__global__ __launch_bounds__(256) void kA(const unsigned* __restrict__ bhist,
                                          unsigned* __restrict__ rsum) {
    __shared__ unsigned s[256];
    int j = blockIdx.x, t = threadIdx.x;
    s[t] = bhist[(size_t)j * NBK1 + t];
    __syncthreads();
    for (int off = 128; off; off >>= 1) {
        if (t < off) s[t] += s[t + off];
        __syncthreads();
    }
    if (t == 0) rsum[j] = s[0];
}

// ---------------- merged scan: bucket bases + per-bucket row scan ----------------
__global__ __launch_bounds__(256) void kC2(unsigned* __restrict__ bhist,
                                           const unsigned* __restrict__ rsum,
                                           unsigned* __restrict__ rbase) {
    __shared__ unsigned sb[256], s[256];
    int j = blockIdx.x, t = threadIdx.x;
    unsigned rc = rsum[t];
    sb[t] = rc;
    __syncthreads();
    for (int off = 1; off < 256; off <<= 1) {
        unsigned v = sb[t]; unsigned u = (t >= off) ? sb[t - off] : 0;
        __syncthreads(); sb[t] = v + u; __syncthreads();
    }
    if (j == 0) {
        rbase[t] = sb[t] - rc;
        if (t == 255) rbase[256] = sb[255];     // == NE
    }
    unsigned rb = (j > 0) ? sb[j - 1] : 0;
    unsigned c = bhist[(size_t)j * NBK1 + t];
    s[t] = c;
    __syncthreads();
    for (int off = 1; off < 256; off <<= 1) {
        unsigned v = s[t]; unsigned u = (t >= off) ? s[t - off] : 0;
        __syncthreads(); s[t] = v + u; __syncthreads();
    }
    bhist[(size_t)j * NBK1 + t] = rb + s[t] - c;
}

// ---------------- bucket partition-scatter, XCD-contiguous chunks + int4 reads ----------------
__global__ __launch_bounds__(256) void k_part(
    const int* __restrict__ ei, const unsigned* __restrict__ base,
    unsigned* __restrict__ tmp) {
    __shared__ unsigned lcur[256];
    int bid = blockIdx.x;
    int c = ((bid & 7) << 5) | (bid >> 3);
    int t = threadIdx.x;
    lcur[t] = base[(size_t)t * NBK1 + c];
    __syncthreads();
    int eb = c * CH, ee = min(NE, eb + CH);
    for (int e = eb + t * 4; e < ee; e += 1024) {
        int4 s4 = *(const int4*)&ei[e];
        int4 d4 = *(const int4*)&ei[NE + e];
        unsigned p0 = atomicAdd(&lcur[((unsigned)d4.x) >> 8], 1u);
        tmp[p0] = ((((unsigned)d4.x) & 255u) << 16) | (unsigned)s4.x;
        unsigned p1 = atomicAdd(&lcur[((unsigned)d4.y) >> 8], 1u);
        tmp[p1] = ((((unsigned)d4.y) & 255u) << 16) | (unsigned)s4.y;
        unsigned p2 = atomicAdd(&lcur[((unsigned)d4.z) >> 8], 1u);
        tmp[p2] = ((((unsigned)d4.z) & 255u) << 16) | (unsigned)s4.z;
        unsigned p3 = atomicAdd(&lcur[((unsigned)d4.w) >> 8], 1u);
        tmp[p3] = ((((unsigned)d4.w) & 255u) << 16) | (unsigned)s4.w;
    }
}

// ---------------- fused: per-bucket CSR finalize || conv layer 0 ----------------
__global__ __launch_bounds__(256) void k_csrconv(
    const unsigned* __restrict__ tmp, const unsigned* __restrict__ rbase,
    int* __restrict__ rp, float* __restrict__ dis, unsigned short* __restrict__ csr,
    const _Float16* __restrict__ xa, const _Float16* __restrict__ cwt,
    _Float16* __restrict__ xw) {
    __shared__ unsigned lbin[256], lofs[256], lcur[256];
    int bid = blockIdx.x;
    if (bid >= NB_BKT) {
        conv_direct(xa, cwt, xw, bid - NB_BKT);
        return;
    }
    int b = bid, t = threadIdx.x;
    unsigned nb0 = rbase[b], nb1 = rbase[b + 1];
    lbin[t] = 0;
    __syncthreads();
    for (unsigned i = nb0 + t; i < nb1; i += 256)
        atomicAdd(&lbin[tmp[i] >> 16], 1u);
    __syncthreads();
    unsigned c = lbin[t];
    lofs[t] = c;
    __syncthreads();
    for (int off = 1; off < 256; off <<= 1) {
        unsigned v = lofs[t]; unsigned u = (t >= off) ? lofs[t - off] : 0;
        __syncthreads(); lofs[t] = v + u; __syncthreads();
    }
    unsigned r = nb0 + lofs[t] - c;
    int node = b * 256 + t;
    if (node < NN) {
        rp[node] = (int)r;
        dis[node] = rsqrtf((float)c + 1.0f);
    }
    lcur[t] = r;
    __syncthreads();
    for (unsigned i = nb0 + t; i < nb1; i += 256) {
        unsigned rec = tmp[i];
        unsigned pos = atomicAdd(&lcur[rec >> 16], 1u);
        csr[pos] = (unsigned short)(rec & 0xffffu);
    }
    if (b == 0 && t == 0) rp[NN] = NE;
}

// ---------------- SpMM oct-structure + fused next-layer conv via MFMA epilogue ----------------
template <bool FIRST, bool LAST>
__global__ __launch_bounds__(256) void k_spmm5(
    const int* __restrict__ rp, const unsigned short* __restrict__ csr,
    unsigned* __restrict__ pack, const float* __restrict__ dis,
    const _Float16* __restrict__ xin, const _Float16* __restrict__ Wt,
    const float* __restrict__ bias, _Float16* __restrict__ xwout,
    const float* __restrict__ lw, const float* __restrict__ lb,
    float* __restrict__ y) {
    __shared__ _Float16 v[16 * 64];
    int lane = threadIdx.x & 63, wvi = threadIdx.x >> 6;
    int o = lane >> 3, g = lane & 7;
    int d0 = blockIdx.x * 16;

    #pragma unroll
    for (int rr = 0; rr < 4; ++rr) {
        int d = d0 + wvi * 4 + rr;
        int beg = rp[d], end = rp[d + 1];
        float dd = dis[d];
        float acc[8];
        #pragma unroll
        for (int i = 0; i < 8; ++i) acc[i] = 0.f;

        int n = end - beg; if (n > 64) n = 64;
        unsigned rv = 0;
        if (lane < n) {
            if (FIRST) {
                int s = csr[beg + lane];
                float w0 = dis[s] * dd;
                rv = (unsigned)s | ((unsigned)__half_as_ushort(__float2half(w0)) << 16);
                pack[beg + lane] = rv;
            } else rv = pack[beg + lane];
        }
        for (int b0 = beg; b0 < end; ) {
            int nb = b0 + 64;
            int n2 = end - nb; if (n2 > 64) n2 = 64;
            unsigned rv2 = 0;
            if (n2 > 0 && lane < n2) {
                if (FIRST) {
                    int s = csr[nb + lane];
                    float w0 = dis[s] * dd;
                    rv2 = (unsigned)s | ((unsigned)__half_as_ushort(__float2half(w0)) << 16);
                    pack[nb + lane] = rv2;
                } else rv2 = pack[nb + lane];
            }
            int nsteps = (n + 7) >> 3;                 // <= 8
            #pragma unroll 4
            for (int jj = 0; jj < nsteps; ++jj) {
                unsigned r = __shfl(rv, jj * 8 + o);   // rv==0 masks idx>=n (w==0)
                float w = __half2float(__ushort_as_half((unsigned short)(r >> 16)));
                h8 xv = *(const h8*)&xin[((r & 0xffffu) << 6) + (g << 3)];
                #pragma unroll
                for (int i = 0; i < 8; ++i) acc[i] += w * (float)xv[i];
            }
            b0 = nb; n = n2; rv = rv2;
        }
        // reduce across the 8 octs -> full sums replicated
        #pragma unroll
        for (int off = 8; off < 64; off <<= 1)
            #pragma unroll
            for (int i = 0; i < 8; ++i) acc[i] += __shfl_xor(acc[i], off);
        // self term
        h8 xs = *(const h8*)&xin[((unsigned)d << 6) + (g << 3)];
        float sn = dd * dd;
        #pragma unroll
        for (int i = 0; i < 8; ++i) acc[i] += sn * (float)xs[i];

        if (LAST) {
            float4 b0v = *(const float4*)&bias[g << 3];
            float4 b1v = *(const float4*)&bias[(g << 3) + 4];
            float vv[8];
            vv[0] = fmaxf(acc[0] + b0v.x, 0.f); vv[1] = fmaxf(acc[1] + b0v.y, 0.f);
            vv[2] = fmaxf(acc[2] + b0v.z, 0.f); vv[3] = fmaxf(acc[3] + b0v.w, 0.f);
            vv[4] = fmaxf(acc[4] + b1v.x, 0.f); vv[5] = fmaxf(acc[5] + b1v.y, 0.f);
            vv[6] = fmaxf(acc[6] + b1v.z, 0.f); vv[7] = fmaxf(acc[7] + b1v.w, 0.f);
            float4 l0 = *(const float4*)&lw[g << 3];
            float4 l1 = *(const float4*)&lw[(g << 3) + 4];
            float t = vv[0] * l0.x + vv[1] * l0.y + vv[2] * l0.z + vv[3] * l0.w
                    + vv[4] * l1.x + vv[5] * l1.y + vv[6] * l1.z + vv[7] * l1.w;
            t += __shfl_xor(t, 1); t += __shfl_xor(t, 2); t += __shfl_xor(t, 4);
            if (lane == 0) y[d] = t + lb[0];
        } else if (o == 0) {
            float4 b0v = *(const float4*)&bias[g << 3];
            float4 b1v = *(const float4*)&bias[(g << 3) + 4];
            h8 hv;
            hv[0] = (_Float16)fmaxf(acc[0] + b0v.x, 0.f);
            hv[1] = (_Float16)fmaxf(acc[1] + b0v.y, 0.f);
            hv[2] = (_Float16)fmaxf(acc[2] + b0v.z, 0.f);
            hv[3] = (_Float16)fmaxf(acc[3] + b0v.w, 0.f);
            hv[4] = (_Float16)fmaxf(acc[4] + b1v.x, 0.f);
            hv[5] = (_Float16)fmaxf(acc[5] + b1v.y, 0.f);
            hv[6] = (_Float16)fmaxf(acc[6] + b1v.z, 0.f);
            hv[7] = (_Float16)fmaxf(acc[7] + b1v.w, 0.f);
            int rl = wvi * 4 + rr;
            *(h8*)&v[rl * 64 + ((g ^ (rl & 7)) << 3)] = hv;
        }
    }

    if (!LAST) {
        __syncthreads();
        int lr = lane & 15, lq = lane >> 4;
        h8 af0 = *(const h8*)&Wt[(size_t)(wvi * 16 + lr) * 64 + lq * 8];
        h8 af1 = *(const h8*)&Wt[(size_t)(wvi * 16 + lr) * 64 + 32 + lq * 8];
        h8 bf0 = *(const h8*)&v[lr * 64 + ((lq ^ (lr & 7)) << 3)];
        h8 bf1 = *(const h8*)&v[lr * 64 + (((4 + lq) ^ (lr & 7)) << 3)];
        f32x4 a = (f32x4){0.f, 0.f, 0.f, 0.f};
        a = MFMA16(af0, bf0, a);
        a = MFMA16(af1, bf1, a);
        int c = wvi * 16 + lq * 4;
        h4 hv;
        hv[0] = (_Float16)a[0]; hv[1] = (_Float16)a[1];
        hv[2] = (_Float16)a[2]; hv[3] = (_Float16)a[3];
        *(h4*)(xwout + (size_t)(d0 + lr) * H + c) = hv;
    }
}

// ---------------- edge scoring: sigmoid(y[src]*y[dst]) ----------------
__global__ void k_out(const float* __restrict__ y, const int* __restrict__ ls,
                      const int* __restrict__ ld, float* __restrict__ out) {
    int e = blockIdx.x * blockDim.x + threadIdx.x;
    if (e < NL) {
        float z = y[ls[e]] * y[ld[e]];
        out[e] = 1.f / (1.f + __expf(-z));
    }
}

static inline size_t up256(size_t x) { return (x + 255) & ~(size_t)255; }

extern "C" void kernel_launch(void* const* d_in, const int* in_sizes, int n_in,
                              void* d_out, int out_size, void* d_ws, size_t ws_size,
                              hipStream_t stream) {
    const float* x_drug = (const float*)d_in[0];
    const float* x_prot = (const float*)d_in[1];
    const float* W_drug = (const float*)d_in[2];
    const float* b_drug = (const float*)d_in[3];
    const float* W_prot = (const float*)d_in[4];
    const float* b_prot = (const float*)d_in[5];
    const float* conv_W = (const float*)d_in[6];
    const float* conv_b = (const float*)d_in[7];
    const float* lin_W  = (const float*)d_in[8];
    const float* lin_b  = (const float*)d_in[9];
    const int*   ei     = (const int*)d_in[10];
    const int*   lsrc   = (const int*)d_in[11];
    const int*   ldst   = (const int*)d_in[12];
    float* out = (float*)d_out;

    char* w = (char*)d_ws;
    size_t off = 0;
    unsigned* bhist = (unsigned*)(w + off); off = up256(off + (size_t)256 * NBK1 * 4);
    unsigned* rsum  = (unsigned*)(w + off); off = up256(off + 256 * 4);
    unsigned* rbase = (unsigned*)(w + off); off = up256(off + 257 * 4);
    unsigned* tmp   = (unsigned*)(w + off); off = up256(off + (size_t)NE * 4);
    unsigned short* csr = (unsigned short*)(w + off); off = up256(off + (size_t)NE * 2);
    unsigned* pack  = (unsigned*)(w + off); off = up256(off + (size_t)NE * 4);
    int*    rp   = (int*)(w + off);    off = up256(off + (size_t)(NN + 1) * 4);
    float*  dis  = (float*)(w + off);  off = up256(off + (size_t)NN * 4);
    _Float16* xa = (_Float16*)(w + off); off = up256(off + (size_t)NN * H * 2);
    _Float16* xb = (_Float16*)(w + off); off = up256(off + (size_t)NN * H * 2);
    _Float16* xw = (_Float16*)(w + off); off = up256(off + (size_t)NN * H * 2);
    float*  y    = (float*)(w + off);  off = up256(off + (size_t)NN * 4);
    _Float16* wdt = (_Float16*)(w + off); off = up256(off + (size_t)64 * F_DRUG * 2);
    _Float16* wpt = (_Float16*)(w + off); off = up256(off + (size_t)64 * F_PROT * 2);
    _Float16* cwt = (_Float16*)(w + off); off = up256(off + (size_t)3 * 64 * 64 * 2);

    k_wprep<<<64, 256, 0, stream>>>(W_drug, W_prot, conv_W, wdt, wpt, cwt);

    // proj_drug || proj_prot || coarse hist
    k_front<<<NB_PROJD + NB_PROJP + NBK1, 256, 0, stream>>>(
        x_drug, wdt, b_drug, x_prot, wpt, b_prot, ei, bhist, xa);

    kA<<<256, 256, 0, stream>>>(bhist, rsum);
    kC2<<<256, 256, 0, stream>>>(bhist, rsum, rbase);

    // bucket partition-scatter (XCD-contiguous chunks, int4 reads)
    k_part<<<NBK1, 256, 0, stream>>>(ei, bhist, tmp);

    // per-bucket CSR finalize || conv layer 0 (xa -> xw0)
    k_csrconv<<<NB_BKT + NB_CONV, 256, 0, stream>>>(
        tmp, rbase, rp, dis, csr, xa, cwt, xw);

    // layer 0: spmm(xw0) -> xw1 (builds pack; conv1 fused via MFMA epilogue)
    k_spmm5<true, false><<<NB_ROW16, 256, 0, stream>>>(
        rp, csr, pack, dis, xw, cwt + 4096, conv_b, xb, nullptr, nullptr, nullptr);
    // layer 1: spmm(xw1) -> xw2 (conv2 fused)
    k_spmm5<false, false><<<NB_ROW16, 256, 0, stream>>>(
        rp, csr, pack, dis, xb, cwt + 8192, conv_b + 64, xa, nullptr, nullptr, nullptr);
    // layer 2: spmm(xw2) -> y (fused lin head)
    k_spmm5<false, true><<<NB_ROW16, 256, 0, stream>>>(
        rp, csr, pack, dis, xa, nullptr, conv_b + 128, nullptr, lin_W, lin_b, y);

    k_out<<<(NL + 255) / 256, 256, 0, stream>>>(y, lsrc, ldst, out);
}